// Round 6
// baseline (197.533 us; speedup 1.0000x reference)
//
#include <hip/hip_runtime.h>
#include <hip/hip_bf16.h>
#include <cstdint>

// Problem constants
#define DIMC  256
#define NH    8
#define HD    32
#define NPIX  2304       // 48*48
#define BATCH 2
#define NSPLIT 6
#define KPS   384        // keys per split (2304/6)
#define KT    32

typedef short s16x8 __attribute__((ext_vector_type(8)));
typedef short s16x4 __attribute__((ext_vector_type(4)));
typedef float f32x4 __attribute__((ext_vector_type(4)));

#define MFMA32(A,B,C) __builtin_amdgcn_mfma_f32_16x16x32_bf16(A,B,C,0,0,0)

#if __has_builtin(__builtin_amdgcn_mfma_f32_16x16x16bf16_1k)
#define HAVE_MFMA16 1
#define MFMA16(A,B,C) __builtin_amdgcn_mfma_f32_16x16x16bf16_1k(A,B,C,0,0,0)
#elif __has_builtin(__builtin_amdgcn_mfma_f32_16x16x16_bf16)
#define HAVE_MFMA16 1
#define MFMA16(A,B,C) __builtin_amdgcn_mfma_f32_16x16x16_bf16(A,B,C,0,0,0)
#else
#define HAVE_MFMA16 0
#endif

#if __has_builtin(__builtin_amdgcn_exp2f)
#define EXP2(x) __builtin_amdgcn_exp2f(x)
#else
#define EXP2(x) exp2f(x)
#endif

// RNA (round-to-nearest-away) bf16 helpers: 1 VALU each.
__device__ inline uint32_t rnau(float x) { return __float_as_uint(x) + 0x8000u; }
__device__ inline uint32_t pk2(uint32_t l_, uint32_t h_) {
  return __builtin_amdgcn_perm(h_, l_, 0x07060302u);
}
__device__ inline float hif(uint32_t a) { return __uint_as_float(a & 0xffff0000u); }

__device__ inline s16x4 pack_bf16x4(const f32x4 p) {
  union { s16x4 s; uint32_t u[2]; } r;
  r.u[0] = pk2(rnau(p[0]), rnau(p[1]));
  r.u[1] = pk2(rnau(p[2]), rnau(p[3]));
  return r.s;
}

// ---------------------------------------------------------------------------
// Pool: x_avg = (x + box3/9 + box5/25 + box7/49)/4, zero-pad, include_pad
// ---------------------------------------------------------------------------
__global__ __launch_bounds__(256) void pool_kernel(const float* __restrict__ x,
                                                   float* __restrict__ xavg) {
  const int plane = blockIdx.x;
  const float* xp = x + (size_t)plane * NPIX;
  __shared__ float sx[NPIX];
  __shared__ float h3[NPIX], h5[NPIX], h7[NPIX];
  const int t = threadIdx.x;
#pragma unroll
  for (int r = 0; r < 9; ++r) sx[r * 256 + t] = xp[r * 256 + t];
  __syncthreads();
#pragma unroll
  for (int r = 0; r < 9; ++r) {
    int p = r * 256 + t;
    int i = p / 48, j = p - i * 48;
    float a3 = 0.f, a5 = 0.f, a7 = 0.f;
#pragma unroll
    for (int dj = -3; dj <= 3; ++dj) {
      int jj = j + dj;
      if (jj < 0 || jj >= 48) continue;
      float v = sx[i * 48 + jj];
      a7 += v;
      if (dj >= -2 && dj <= 2) a5 += v;
      if (dj >= -1 && dj <= 1) a3 += v;
    }
    h3[p] = a3; h5[p] = a5; h7[p] = a7;
  }
  __syncthreads();
#pragma unroll
  for (int r = 0; r < 9; ++r) {
    int p = r * 256 + t;
    int i = p / 48, j = p - i * 48;
    float b3 = 0.f, b5 = 0.f, b7 = 0.f;
#pragma unroll
    for (int di = -3; di <= 3; ++di) {
      int ii = i + di;
      if (ii < 0 || ii >= 48) continue;
      int q = ii * 48 + j;
      b7 += h7[q];
      if (di >= -2 && di <= 2) b5 += h5[q];
      if (di >= -1 && di <= 1) b3 += h3[q];
    }
    xavg[(size_t)plane * NPIX + p] =
        0.25f * (sx[p] + b3 * (1.f / 9.f) + b5 * (1.f / 25.f) + b7 * (1.f / 49.f));
  }
}

// ---------------------------------------------------------------------------
// Fused converts: blocks 0..287 tconv(x), 288..575 tconv(xavg), 576..703 wconv
// ---------------------------------------------------------------------------
__global__ __launch_bounds__(256) void conv_all(
    const float* __restrict__ x, const float* __restrict__ xavg,
    const float* __restrict__ qw, const float* __restrict__ kvw,
    const float* __restrict__ pw_,
    short* __restrict__ Xh, short* __restrict__ Xl,
    short* __restrict__ Ah, short* __restrict__ Al,
    short* __restrict__ Wth, short* __restrict__ Wtl) {
  const int bx = blockIdx.x;
  const int t = threadIdx.x;
  if (bx < 576) {
    const float* src = (bx < 288) ? x : xavg;
    short* dhi = (bx < 288) ? Xh : Ah;
    short* dlo = (bx < 288) ? Xl : Al;
    const int bb = (bx < 288) ? bx : bx - 288;
    const int n0 = (bb % 36) * 64, c0 = ((bb / 36) & 3) * 64, b = bb / 144;
    __shared__ __align__(16) float T[64][68];
    {
      const int c = t >> 2, n4 = (t & 3) * 16;
      const float* sp = src + ((size_t)b * DIMC + c0 + c) * NPIX + n0 + n4;
#pragma unroll
      for (int i2 = 0; i2 < 4; ++i2)
        *(f32x4*)&T[c][n4 + i2 * 4] = *(const f32x4*)(sp + i2 * 4);
    }
    __syncthreads();
    {
      const int n = t >> 2, c4 = (t & 3) * 16;
      float v[16];
#pragma unroll
      for (int i = 0; i < 16; ++i) v[i] = T[c4 + i][n];
      uint32_t a[16], al[16];
#pragma unroll
      for (int i = 0; i < 16; ++i) a[i] = rnau(v[i]);
#pragma unroll
      for (int i = 0; i < 16; ++i) al[i] = rnau(v[i] - hif(a[i]));
      union { s16x8 s; uint32_t u[4]; } H0, H1, L0, L1;
#pragma unroll
      for (int j = 0; j < 4; ++j) {
        H0.u[j] = pk2(a[2 * j], a[2 * j + 1]);
        H1.u[j] = pk2(a[8 + 2 * j], a[8 + 2 * j + 1]);
        L0.u[j] = pk2(al[2 * j], al[2 * j + 1]);
        L1.u[j] = pk2(al[8 + 2 * j], al[8 + 2 * j + 1]);
      }
      const size_t off = ((size_t)b * NPIX + n0 + n) * DIMC + c0 + c4;
      *(s16x8*)(dhi + off) = H0.s; *(s16x8*)(dhi + off + 8) = H1.s;
      *(s16x8*)(dlo + off) = L0.s; *(s16x8*)(dlo + off + 8) = L1.s;
    }
  } else {
    const int idx = ((bx - 576) * 256 + t) * 8;
    const float* s;
    int off;
    if (idx < 65536)       { s = qw;  off = idx; }
    else if (idx < 196608) { s = kvw; off = idx - 65536; }
    else                   { s = pw_; off = idx - 196608; }
    f32x4 x0 = *(const f32x4*)(s + off);
    f32x4 x1 = *(const f32x4*)(s + off + 4);
    float v[8] = {x0[0], x0[1], x0[2], x0[3], x1[0], x1[1], x1[2], x1[3]};
    uint32_t a[8], al[8];
#pragma unroll
    for (int i = 0; i < 8; ++i) a[i] = rnau(v[i]);
#pragma unroll
    for (int i = 0; i < 8; ++i) al[i] = rnau(v[i] - hif(a[i]));
    union { s16x8 s; uint32_t u[4]; } H, L;
#pragma unroll
    for (int j = 0; j < 4; ++j) {
      H.u[j] = pk2(a[2 * j], a[2 * j + 1]);
      L.u[j] = pk2(al[2 * j], al[2 * j + 1]);
    }
    *(s16x8*)(Wth + idx) = H.s;
    *(s16x8*)(Wtl + idx) = L.s;
  }
}

// ---------------------------------------------------------------------------
// GEMM body: Out[o][n] = sum_c W[o][c]*In[n][c] (+bias), hi/lo bf16, 3 MFMAs.
// ---------------------------------------------------------------------------
__device__ __forceinline__ void gemm_body(
    const short* __restrict__ Wh, const short* __restrict__ Wl,
    const float* __restrict__ bias,
    const short* __restrict__ Inh, const short* __restrict__ Inl,
    float* __restrict__ outf, short* __restrict__ d1, short* __restrict__ d2,
    int mode, float scale, int n0, int o0, int b, float (*Cl)[68]) {
  const int tid = threadIdx.x;
  const int wave = tid >> 6, lane = tid & 63;
  const int g = lane >> 4, q = lane & 15;

  const short* wph = Wh + ((o0 + wave * 16 + q) * DIMC + g * 8);
  const short* wpl = Wl + ((o0 + wave * 16 + q) * DIMC + g * 8);
  const short* iph = Inh + ((size_t)(b * NPIX + n0 + q) * DIMC + g * 8);
  const short* ipl = Inl + ((size_t)(b * NPIX + n0 + q) * DIMC + g * 8);

  f32x4 acc[4] = {{0,0,0,0},{0,0,0,0},{0,0,0,0},{0,0,0,0}};
#pragma unroll
  for (int c0 = 0; c0 < DIMC; c0 += 32) {
    s16x8 ah = *(const s16x8*)(wph + c0);
    s16x8 al = *(const s16x8*)(wpl + c0);
#pragma unroll
    for (int st = 0; st < 4; ++st) {
      s16x8 bh_ = *(const s16x8*)(iph + (size_t)st * 16 * DIMC + c0);
      s16x8 bl_ = *(const s16x8*)(ipl + (size_t)st * 16 * DIMC + c0);
      acc[st] = MFMA32(ah, bh_, acc[st]);
      acc[st] = MFMA32(ah, bl_, acc[st]);
      acc[st] = MFMA32(al, bh_, acc[st]);
    }
  }
#pragma unroll
  for (int st = 0; st < 4; ++st)
#pragma unroll
    for (int r = 0; r < 4; ++r)
      Cl[wave * 16 + g * 4 + r][st * 16 + q] = acc[st][r];
  __syncthreads();

  if (mode == 0) {
    const int o = tid >> 2, nc = (tid & 3) * 16;
    const float bv = bias[o0 + o];
    float* op = outf + ((size_t)b * DIMC + o0 + o) * NPIX + n0 + nc;
#pragma unroll
    for (int i2 = 0; i2 < 4; ++i2) {
      f32x4 v = *(const f32x4*)&Cl[o][nc + i2 * 4];
      v[0] += bv; v[1] += bv; v[2] += bv; v[3] += bv;
      *(f32x4*)(op + i2 * 4) = v;
    }
  } else if (o0 < 256) {
    // Q or K: (C+bias)*scale, hi-only, layout [bh][n][32]
    const int n = tid >> 1, oq = tid & 1;
    const int h = o0 >> 5;
    const float* bp = bias + o0 + oq * 16;
    float v[16];
#pragma unroll
    for (int i = 0; i < 16; ++i) v[i] = (Cl[oq * 16 + i][n] + bp[i]) * scale;
    uint32_t a[16];
#pragma unroll
    for (int i = 0; i < 16; ++i) a[i] = rnau(v[i]);
    union { s16x8 s; uint32_t u[4]; } H0, H1;
#pragma unroll
    for (int j = 0; j < 4; ++j) {
      H0.u[j] = pk2(a[2 * j], a[2 * j + 1]);
      H1.u[j] = pk2(a[8 + 2 * j], a[8 + 2 * j + 1]);
    }
    const size_t off = ((size_t)((b * 8 + h) * NPIX + n0 + n)) * HD + oq * 16;
    *(s16x8*)(d1 + off) = H0.s; *(s16x8*)(d1 + off + 8) = H1.s;
  } else {
    // V hi-only: dst [bh][d][n]
    const int o = tid >> 2, nc = (tid & 3) * 16;
    const int h = (o0 - 256) >> 5;
    const float bv = bias[o0 + o];
    float v[16];
#pragma unroll
    for (int i2 = 0; i2 < 4; ++i2) {
      f32x4 t4 = *(const f32x4*)&Cl[o][nc + i2 * 4];
      v[i2 * 4 + 0] = t4[0] + bv; v[i2 * 4 + 1] = t4[1] + bv;
      v[i2 * 4 + 2] = t4[2] + bv; v[i2 * 4 + 3] = t4[3] + bv;
    }
    uint32_t a[16];
#pragma unroll
    for (int i = 0; i < 16; ++i) a[i] = rnau(v[i]);
    union { s16x8 s; uint32_t u[4]; } H0, H1;
#pragma unroll
    for (int j = 0; j < 4; ++j) {
      H0.u[j] = pk2(a[2 * j], a[2 * j + 1]);
      H1.u[j] = pk2(a[8 + 2 * j], a[8 + 2 * j + 1]);
    }
    const size_t off = ((size_t)((b * 8 + h) * HD + o)) * NPIX + n0 + nc;
    *(s16x8*)(d2 + off) = H0.s; *(s16x8*)(d2 + off + 8) = H1.s;
  }
}

__global__ __launch_bounds__(128) void gemm_qkv(
    const short* __restrict__ Wth, const short* __restrict__ Wtl,
    const float* __restrict__ q_b, const float* __restrict__ kv_b,
    const short* __restrict__ Xh, const short* __restrict__ Xl,
    const short* __restrict__ Ah, const short* __restrict__ Al,
    short* __restrict__ Qhi, short* __restrict__ Khi, short* __restrict__ Vhi,
    float qscale) {
  __shared__ __align__(16) float Cl[32][68];
  const int by = blockIdx.y;
  if (by < 8) {
    gemm_body(Wth, Wtl, q_b, Xh, Xl, nullptr, Qhi, nullptr,
              2, qscale, blockIdx.x * 64, by * 32, blockIdx.z, Cl);
  } else {
    gemm_body(Wth + 65536, Wtl + 65536, kv_b, Ah, Al, nullptr, Khi, Vhi,
              2, 1.0f, blockIdx.x * 64, (by - 8) * 32, blockIdx.z, Cl);
  }
}

__global__ __launch_bounds__(128) void gemm_proj(
    const short* __restrict__ Wh, const short* __restrict__ Wl,
    const float* __restrict__ bias,
    const short* __restrict__ Zh, const short* __restrict__ Zl,
    float* __restrict__ out) {
  __shared__ __align__(16) float Cl[32][68];
  gemm_body(Wh, Wl, bias, Zh, Zl, out, nullptr, nullptr,
            0, 1.0f, blockIdx.x * 64, blockIdx.y * 32, blockIdx.z, Cl);
}

// ---------------------------------------------------------------------------
// MFMA flash attention, no-max softmax, NO LDS round-trip:
// PV uses K=16 MFMAs whose B-operand layout (k=g*4+j, n=lane&15) exactly
// matches the S C-layout (row=g*4+r, col=lane&15) -> P-frag straight from
// own registers. Wave owns 32 q-rows (2 tiles) sharing one K/V stream.
// ---------------------------------------------------------------------------
__global__ __launch_bounds__(256) void attn_mfma(
    const short* __restrict__ Qhi,   // [bh][n][32]
    const short* __restrict__ Khi,   // [bh][n][32]
    const short* __restrict__ Vhi,   // [bh][32][N]
    float* __restrict__ part_o,      // [row][NSPLIT][32]
    float* __restrict__ part_l) {    // [row][NSPLIT]
  const int sb = blockIdx.x;        // 0..287
  const int bh = sb / 18;
  const int qb = sb % 18;           // 128-row block
  const int split = blockIdx.y;     // 0..5
  const int tid = threadIdx.x;
  const int wave = tid >> 6, lane = tid & 63;
  const int g = lane >> 4, q = lane & 15;
  const int base = qb * 128 + wave * 32;

#if !HAVE_MFMA16
  __shared__ __align__(16) short Plds[4][2][16 * 40];
  short* pwA = &Plds[wave][0][0];
  short* pwB = &Plds[wave][1][0];
#endif

  const size_t qoff = ((size_t)bh * NPIX + base + q) * HD + g * 8;
  const s16x8 qhA = *(const s16x8*)(Qhi + qoff);
  const s16x8 qhB = *(const s16x8*)(Qhi + qoff + 16 * HD);

  const short* kbase = Khi + ((size_t)bh * NPIX + split * KPS + q) * HD + g * 8;
  const short* vbase = Vhi + ((size_t)bh * HD + q) * NPIX + split * KPS;

  const f32x4 Z4 = {0.f, 0.f, 0.f, 0.f};
  f32x4 OA0 = Z4, OA1 = Z4, OB0 = Z4, OB1 = Z4;
  f32x4 lva = Z4, lvb = Z4;

  for (int t = 0; t < KPS / KT; ++t) {
    const s16x8 k0 = *(const s16x8*)(kbase);
    const s16x8 k1 = *(const s16x8*)(kbase + 16 * HD);
#if HAVE_MFMA16
    const s16x4 va0 = *(const s16x4*)(vbase + g * 4);              // d 0..15, keys 0..15
    const s16x4 va1 = *(const s16x4*)(vbase + 16 + g * 4);         // keys 16..31
    const s16x4 vb0 = *(const s16x4*)(vbase + 16 * NPIX + g * 4);  // d 16..31
    const s16x4 vb1 = *(const s16x4*)(vbase + 16 * NPIX + 16 + g * 4);
#else
    const s16x8 v0 = *(const s16x8*)(vbase + g * 8);
    const s16x8 v1 = *(const s16x8*)(vbase + 16 * NPIX + g * 8);
#endif
    kbase += KT * HD;
    vbase += KT;

    f32x4 SA0 = MFMA32(k0, qhA, Z4);   // keys 0..15  x qA
    f32x4 SA1 = MFMA32(k1, qhA, Z4);   // keys 16..31 x qA
    f32x4 SB0 = MFMA32(k0, qhB, Z4);
    f32x4 SB1 = MFMA32(k1, qhB, Z4);

    f32x4 pA0, pA1, pB0, pB1;
#pragma unroll
    for (int r = 0; r < 4; ++r) {
      pA0[r] = EXP2(SA0[r]); pA1[r] = EXP2(SA1[r]);
      pB0[r] = EXP2(SB0[r]); pB1[r] = EXP2(SB1[r]);
    }
    lva += pA0 + pA1;
    lvb += pB0 + pB1;

#if HAVE_MFMA16
    const s16x4 fA0 = pack_bf16x4(pA0), fA1 = pack_bf16x4(pA1);
    const s16x4 fB0 = pack_bf16x4(pB0), fB1 = pack_bf16x4(pB1);
    OA0 = MFMA16(va0, fA0, OA0); OA0 = MFMA16(va1, fA1, OA0);
    OA1 = MFMA16(vb0, fA0, OA1); OA1 = MFMA16(vb1, fA1, OA1);
    OB0 = MFMA16(va0, fB0, OB0); OB0 = MFMA16(va1, fB1, OB0);
    OB1 = MFMA16(vb0, fB0, OB1); OB1 = MFMA16(vb1, fB1, OB1);
#else
    {
      union { s16x4 s; uint32_t u[2]; } a0, a1;
      a0.s = pack_bf16x4(pA0); a1.s = pack_bf16x4(pA1);
      *(uint2*)&pwA[q * 40 + g * 4]      = make_uint2(a0.u[0], a0.u[1]);
      *(uint2*)&pwA[q * 40 + 16 + g * 4] = make_uint2(a1.u[0], a1.u[1]);
      a0.s = pack_bf16x4(pB0); a1.s = pack_bf16x4(pB1);
      *(uint2*)&pwB[q * 40 + g * 4]      = make_uint2(a0.u[0], a0.u[1]);
      *(uint2*)&pwB[q * 40 + 16 + g * 4] = make_uint2(a1.u[0], a1.u[1]);
    }
    const s16x8 pfA = *(const s16x8*)&pwA[q * 40 + g * 8];
    const s16x8 pfB = *(const s16x8*)&pwB[q * 40 + g * 8];
    OA0 = MFMA32(v0, pfA, OA0); OA1 = MFMA32(v1, pfA, OA1);
    OB0 = MFMA32(v0, pfB, OB0); OB1 = MFMA32(v1, pfB, OB1);
#endif
  }

  float lA = (lva[0] + lva[1]) + (lva[2] + lva[3]);
  float lB = (lvb[0] + lvb[1]) + (lvb[2] + lvb[3]);
  lA += __shfl_xor(lA, 16); lA += __shfl_xor(lA, 32);
  lB += __shfl_xor(lB, 16); lB += __shfl_xor(lB, 32);

  const int rowA = bh * NPIX + base + q;
  const int rowB = rowA + 16;
  float* poA = part_o + ((size_t)rowA * NSPLIT + split) * HD;
  float* poB = part_o + ((size_t)rowB * NSPLIT + split) * HD;
  *(f32x4*)(poA + g * 4) = OA0;
  *(f32x4*)(poA + 16 + g * 4) = OA1;
  *(f32x4*)(poB + g * 4) = OB0;
  *(f32x4*)(poB + 16 + g * 4) = OB1;
  if (g == 0) {
    part_l[(size_t)rowA * NSPLIT + split] = lA;
    part_l[(size_t)rowB * NSPLIT + split] = lB;
  }
}

// ---------------------------------------------------------------------------
// Merge splits (plain sums) and emit SCRAMBLED z hi/lo [b][p][256]:
// p=(n%9)*256+head*32+dd, c=n/9.
// ---------------------------------------------------------------------------
__global__ __launch_bounds__(288) void attn_merge(const float* __restrict__ part_o,
                                                  const float* __restrict__ part_l,
                                                  short* __restrict__ zh,
                                                  short* __restrict__ zl) {
  const int blk = blockIdx.x;          // 128 = 16 bh * 8
  const int bh = blk >> 3;
  const int n0 = (blk & 7) * 288;
  const int head = bh & 7, b = bh >> 3;
  const int t = threadIdx.x;
  __shared__ __align__(16) float T[288][36];
  {
    const int idx = bh * NPIX + n0 + t;
    const float* pl = part_l + (size_t)idx * NSPLIT;
    float L = 0.f;
#pragma unroll
    for (int s = 0; s < NSPLIT; ++s) L += pl[s];
    const float inv = 1.f / L;
    const float* po = part_o + (size_t)idx * (NSPLIT * HD);
#pragma unroll
    for (int u = 0; u < 8; ++u) {
      f32x4 v = {0.f, 0.f, 0.f, 0.f};
#pragma unroll
      for (int s = 0; s < NSPLIT; ++s)
        v += *(const f32x4*)(po + s * HD + u * 4);
      v[0] *= inv; v[1] *= inv; v[2] *= inv; v[3] *= inv;
      *(f32x4*)&T[t][u * 4] = v;
    }
  }
  __syncthreads();
  {
    const int r9 = t / 32, dd = t & 31;
    const int p = r9 * 256 + head * HD + dd;
    const int c0 = n0 / 9;
    float v[32];
#pragma unroll
    for (int j = 0; j < 32; ++j) v[j] = T[9 * j + r9][dd];
    uint32_t a[32], al[32];
#pragma unroll
    for (int j = 0; j < 32; ++j) a[j] = rnau(v[j]);
#pragma unroll
    for (int j = 0; j < 32; ++j) al[j] = rnau(v[j] - hif(a[j]));
    const size_t off = ((size_t)b * NPIX + p) * DIMC + c0;
#pragma unroll
    for (int c8 = 0; c8 < 4; ++c8) {
      union { s16x8 s; uint32_t u[4]; } H, L;
#pragma unroll
      for (int j = 0; j < 4; ++j) {
        H.u[j] = pk2(a[c8 * 8 + 2 * j], a[c8 * 8 + 2 * j + 1]);
        L.u[j] = pk2(al[c8 * 8 + 2 * j], al[c8 * 8 + 2 * j + 1]);
      }
      *(s16x8*)(zh + off + c8 * 8) = H.s;
      *(s16x8*)(zl + off + c8 * 8) = L.s;
    }
  }
}

// ---------------------------------------------------------------------------
extern "C" void kernel_launch(void* const* d_in, const int* in_sizes, int n_in,
                              void* d_out, int out_size, void* d_ws, size_t ws_size,
                              hipStream_t stream) {
  const float* x      = (const float*)d_in[0];
  const float* q_w    = (const float*)d_in[1];
  const float* q_b    = (const float*)d_in[2];
  const float* kv_w   = (const float*)d_in[3];
  const float* kv_b   = (const float*)d_in[4];
  const float* proj_w = (const float*)d_in[5];
  const float* proj_b = (const float*)d_in[6];
  float* out = (float*)d_out;

  // Workspace (42.0 MB total; 43.6 MB proven available in R1).
  // [0, 28.3MB): prologue xavg/Xh/Xl/Ah/Al (14.2MB), then part_o (NSPLIT=6).
  char* w = (char*)d_ws;
  float* xavg = (float*)w;                       // 4,718,592
  short* Xh   = (short*)(w + 4718592);
  short* Xl   = (short*)(w + 7077888);
  short* Ah   = (short*)(w + 9437184);
  short* Al   = (short*)(w + 11796480);          // ends 14,155,776
  float* part_o = (float*)w;                     // 28,311,552 (aliases above)
  short* Wth  = (short*)(w + 28311552);          // 524,288
  short* Wtl  = (short*)(w + 28835840);
  short* Qhi  = (short*)(w + 29360128);          // 2,359,296
  short* Khi  = (short*)(w + 31719424);
  short* Vhi  = (short*)(w + 34078720);
  float* part_l = (float*)(w + 36438016);        // 884,736
  short* Zh   = (short*)(w + 37322752);
  short* Zl   = (short*)(w + 39682048);          // ends 42,041,344

  const float qscale = 0.17677669529663689f * 1.4426950408889634f; // d^-0.5*log2(e)

  pool_kernel<<<BATCH * DIMC, 256, 0, stream>>>(x, xavg);
  conv_all<<<704, 256, 0, stream>>>(x, xavg, q_w, kv_w, proj_w,
                                    Xh, Xl, Ah, Al, Wth, Wtl);
  gemm_qkv<<<dim3(36, 24, 2), 128, 0, stream>>>(Wth, Wtl, q_b, kv_b,
                                                Xh, Xl, Ah, Al,
                                                Qhi, Khi, Vhi, qscale);
  attn_mfma<<<dim3(288, NSPLIT), 256, 0, stream>>>(Qhi, Khi, Vhi, part_o, part_l);
  attn_merge<<<128, 288, 0, stream>>>(part_o, part_l, Zh, Zl);
  gemm_proj<<<dim3(36, 8, 2), 128, 0, stream>>>(Wth + 196608, Wtl + 196608, proj_b,
                                                Zh, Zl, out);
}

// Round 8
// 196.566 us; speedup vs baseline: 1.0049x; 1.0049x over previous
//
#include <hip/hip_runtime.h>
#include <hip/hip_bf16.h>
#include <cstdint>

// Problem constants
#define DIMC  256
#define NH    8
#define HD    32
#define NPIX  2304       // 48*48
#define BATCH 2
#define NSPLIT 4
#define KPS   576        // keys per split (2304/4)
#define KT    32

typedef short s16x8 __attribute__((ext_vector_type(8)));
typedef short s16x4 __attribute__((ext_vector_type(4)));
typedef float f32x4 __attribute__((ext_vector_type(4)));

#define MFMA32(A,B,C) __builtin_amdgcn_mfma_f32_16x16x32_bf16(A,B,C,0,0,0)

// K=16 bf16 MFMA: present in the DEVICE pass (verified R6: LDS=0 path ran,
// absmax correct). The HOST pass doesn't register these builtins, so give it
// a typecheck-only dummy (never executed on host).
#if __has_builtin(__builtin_amdgcn_mfma_f32_16x16x16bf16_1k)
#define MFMA16(A,B,C) __builtin_amdgcn_mfma_f32_16x16x16bf16_1k(A,B,C,0,0,0)
#elif __has_builtin(__builtin_amdgcn_mfma_f32_16x16x16_bf16)
#define MFMA16(A,B,C) __builtin_amdgcn_mfma_f32_16x16x16_bf16(A,B,C,0,0,0)
#else
static inline __device__ __host__ f32x4 mfma16_host_stub(s16x4, s16x4, f32x4 c) { return c; }
#define MFMA16(A,B,C) mfma16_host_stub(A,B,C)
#endif

// RNA (round-to-nearest-away) bf16 helpers: 1 VALU each.
__device__ inline uint32_t rnau(float x) { return __float_as_uint(x) + 0x8000u; }
__device__ inline uint32_t pk2(uint32_t l_, uint32_t h_) {
  return __builtin_amdgcn_perm(h_, l_, 0x07060302u);
}
__device__ inline float hif(uint32_t a) { return __uint_as_float(a & 0xffff0000u); }

__device__ inline s16x4 pack_bf16x4(const f32x4 p) {
  union { s16x4 s; uint32_t u[2]; } r;
  r.u[0] = pk2(rnau(p[0]), rnau(p[1]));
  r.u[1] = pk2(rnau(p[2]), rnau(p[3]));
  return r.s;
}

// ---------------------------------------------------------------------------
// Pool: x_avg = (x + box3/9 + box5/25 + box7/49)/4, zero-pad, include_pad
// ---------------------------------------------------------------------------
__global__ __launch_bounds__(256) void pool_kernel(const float* __restrict__ x,
                                                   float* __restrict__ xavg) {
  const int plane = blockIdx.x;
  const float* xp = x + (size_t)plane * NPIX;
  __shared__ float sx[NPIX];
  __shared__ float h3[NPIX], h5[NPIX], h7[NPIX];
  const int t = threadIdx.x;
#pragma unroll
  for (int r = 0; r < 9; ++r) sx[r * 256 + t] = xp[r * 256 + t];
  __syncthreads();
#pragma unroll
  for (int r = 0; r < 9; ++r) {
    int p = r * 256 + t;
    int i = p / 48, j = p - i * 48;
    float a3 = 0.f, a5 = 0.f, a7 = 0.f;
#pragma unroll
    for (int dj = -3; dj <= 3; ++dj) {
      int jj = j + dj;
      if (jj < 0 || jj >= 48) continue;
      float v = sx[i * 48 + jj];
      a7 += v;
      if (dj >= -2 && dj <= 2) a5 += v;
      if (dj >= -1 && dj <= 1) a3 += v;
    }
    h3[p] = a3; h5[p] = a5; h7[p] = a7;
  }
  __syncthreads();
#pragma unroll
  for (int r = 0; r < 9; ++r) {
    int p = r * 256 + t;
    int i = p / 48, j = p - i * 48;
    float b3 = 0.f, b5 = 0.f, b7 = 0.f;
#pragma unroll
    for (int di = -3; di <= 3; ++di) {
      int ii = i + di;
      if (ii < 0 || ii >= 48) continue;
      int q = ii * 48 + j;
      b7 += h7[q];
      if (di >= -2 && di <= 2) b5 += h5[q];
      if (di >= -1 && di <= 1) b3 += h3[q];
    }
    xavg[(size_t)plane * NPIX + p] =
        0.25f * (sx[p] + b3 * (1.f / 9.f) + b5 * (1.f / 25.f) + b7 * (1.f / 49.f));
  }
}

// ---------------------------------------------------------------------------
// Fused converts: blocks 0..287 tconv(x), 288..575 tconv(xavg), 576..703 wconv
// ---------------------------------------------------------------------------
__global__ __launch_bounds__(256) void conv_all(
    const float* __restrict__ x, const float* __restrict__ xavg,
    const float* __restrict__ qw, const float* __restrict__ kvw,
    const float* __restrict__ pw_,
    short* __restrict__ Xh, short* __restrict__ Xl,
    short* __restrict__ Ah, short* __restrict__ Al,
    short* __restrict__ Wth, short* __restrict__ Wtl) {
  const int bx = blockIdx.x;
  const int t = threadIdx.x;
  if (bx < 576) {
    const float* src = (bx < 288) ? x : xavg;
    short* dhi = (bx < 288) ? Xh : Ah;
    short* dlo = (bx < 288) ? Xl : Al;
    const int bb = (bx < 288) ? bx : bx - 288;
    const int n0 = (bb % 36) * 64, c0 = ((bb / 36) & 3) * 64, b = bb / 144;
    __shared__ __align__(16) float T[64][68];
    {
      const int c = t >> 2, n4 = (t & 3) * 16;
      const float* sp = src + ((size_t)b * DIMC + c0 + c) * NPIX + n0 + n4;
#pragma unroll
      for (int i2 = 0; i2 < 4; ++i2)
        *(f32x4*)&T[c][n4 + i2 * 4] = *(const f32x4*)(sp + i2 * 4);
    }
    __syncthreads();
    {
      const int n = t >> 2, c4 = (t & 3) * 16;
      float v[16];
#pragma unroll
      for (int i = 0; i < 16; ++i) v[i] = T[c4 + i][n];
      uint32_t a[16], al[16];
#pragma unroll
      for (int i = 0; i < 16; ++i) a[i] = rnau(v[i]);
#pragma unroll
      for (int i = 0; i < 16; ++i) al[i] = rnau(v[i] - hif(a[i]));
      union { s16x8 s; uint32_t u[4]; } H0, H1, L0, L1;
#pragma unroll
      for (int j = 0; j < 4; ++j) {
        H0.u[j] = pk2(a[2 * j], a[2 * j + 1]);
        H1.u[j] = pk2(a[8 + 2 * j], a[8 + 2 * j + 1]);
        L0.u[j] = pk2(al[2 * j], al[2 * j + 1]);
        L1.u[j] = pk2(al[8 + 2 * j], al[8 + 2 * j + 1]);
      }
      const size_t off = ((size_t)b * NPIX + n0 + n) * DIMC + c0 + c4;
      *(s16x8*)(dhi + off) = H0.s; *(s16x8*)(dhi + off + 8) = H1.s;
      *(s16x8*)(dlo + off) = L0.s; *(s16x8*)(dlo + off + 8) = L1.s;
    }
  } else {
    const int idx = ((bx - 576) * 256 + t) * 8;
    const float* s;
    int off;
    if (idx < 65536)       { s = qw;  off = idx; }
    else if (idx < 196608) { s = kvw; off = idx - 65536; }
    else                   { s = pw_; off = idx - 196608; }
    f32x4 x0 = *(const f32x4*)(s + off);
    f32x4 x1 = *(const f32x4*)(s + off + 4);
    float v[8] = {x0[0], x0[1], x0[2], x0[3], x1[0], x1[1], x1[2], x1[3]};
    uint32_t a[8], al[8];
#pragma unroll
    for (int i = 0; i < 8; ++i) a[i] = rnau(v[i]);
#pragma unroll
    for (int i = 0; i < 8; ++i) al[i] = rnau(v[i] - hif(a[i]));
    union { s16x8 s; uint32_t u[4]; } H, L;
#pragma unroll
    for (int j = 0; j < 4; ++j) {
      H.u[j] = pk2(a[2 * j], a[2 * j + 1]);
      L.u[j] = pk2(al[2 * j], al[2 * j + 1]);
    }
    *(s16x8*)(Wth + idx) = H.s;
    *(s16x8*)(Wtl + idx) = L.s;
  }
}

// ---------------------------------------------------------------------------
// GEMM body: Out[o][n] = sum_c W[o][c]*In[n][c] (+bias), hi/lo bf16, 3 MFMAs.
// ---------------------------------------------------------------------------
__device__ __forceinline__ void gemm_body(
    const short* __restrict__ Wh, const short* __restrict__ Wl,
    const float* __restrict__ bias,
    const short* __restrict__ Inh, const short* __restrict__ Inl,
    float* __restrict__ outf, short* __restrict__ d1, short* __restrict__ d2,
    int mode, float scale, int n0, int o0, int b, float (*Cl)[68]) {
  const int tid = threadIdx.x;
  const int wave = tid >> 6, lane = tid & 63;
  const int g = lane >> 4, q = lane & 15;

  const short* wph = Wh + ((o0 + wave * 16 + q) * DIMC + g * 8);
  const short* wpl = Wl + ((o0 + wave * 16 + q) * DIMC + g * 8);
  const short* iph = Inh + ((size_t)(b * NPIX + n0 + q) * DIMC + g * 8);
  const short* ipl = Inl + ((size_t)(b * NPIX + n0 + q) * DIMC + g * 8);

  f32x4 acc[4] = {{0,0,0,0},{0,0,0,0},{0,0,0,0},{0,0,0,0}};
#pragma unroll
  for (int c0 = 0; c0 < DIMC; c0 += 32) {
    s16x8 ah = *(const s16x8*)(wph + c0);
    s16x8 al = *(const s16x8*)(wpl + c0);
#pragma unroll
    for (int st = 0; st < 4; ++st) {
      s16x8 bh_ = *(const s16x8*)(iph + (size_t)st * 16 * DIMC + c0);
      s16x8 bl_ = *(const s16x8*)(ipl + (size_t)st * 16 * DIMC + c0);
      acc[st] = MFMA32(ah, bh_, acc[st]);
      acc[st] = MFMA32(ah, bl_, acc[st]);
      acc[st] = MFMA32(al, bh_, acc[st]);
    }
  }
#pragma unroll
  for (int st = 0; st < 4; ++st)
#pragma unroll
    for (int r = 0; r < 4; ++r)
      Cl[wave * 16 + g * 4 + r][st * 16 + q] = acc[st][r];
  __syncthreads();

  if (mode == 0) {
    const int o = tid >> 2, nc = (tid & 3) * 16;
    const float bv = bias[o0 + o];
    float* op = outf + ((size_t)b * DIMC + o0 + o) * NPIX + n0 + nc;
#pragma unroll
    for (int i2 = 0; i2 < 4; ++i2) {
      f32x4 v = *(const f32x4*)&Cl[o][nc + i2 * 4];
      v[0] += bv; v[1] += bv; v[2] += bv; v[3] += bv;
      *(f32x4*)(op + i2 * 4) = v;
    }
  } else if (o0 < 256) {
    // Q or K: (C+bias)*scale, hi-only, layout [bh][n][32]
    const int n = tid >> 1, oq = tid & 1;
    const int h = o0 >> 5;
    const float* bp = bias + o0 + oq * 16;
    float v[16];
#pragma unroll
    for (int i = 0; i < 16; ++i) v[i] = (Cl[oq * 16 + i][n] + bp[i]) * scale;
    uint32_t a[16];
#pragma unroll
    for (int i = 0; i < 16; ++i) a[i] = rnau(v[i]);
    union { s16x8 s; uint32_t u[4]; } H0, H1;
#pragma unroll
    for (int j = 0; j < 4; ++j) {
      H0.u[j] = pk2(a[2 * j], a[2 * j + 1]);
      H1.u[j] = pk2(a[8 + 2 * j], a[8 + 2 * j + 1]);
    }
    const size_t off = ((size_t)((b * 8 + h) * NPIX + n0 + n)) * HD + oq * 16;
    *(s16x8*)(d1 + off) = H0.s; *(s16x8*)(d1 + off + 8) = H1.s;
  } else {
    // V hi-only: dst [bh][d][n]
    const int o = tid >> 2, nc = (tid & 3) * 16;
    const int h = (o0 - 256) >> 5;
    const float bv = bias[o0 + o];
    float v[16];
#pragma unroll
    for (int i2 = 0; i2 < 4; ++i2) {
      f32x4 t4 = *(const f32x4*)&Cl[o][nc + i2 * 4];
      v[i2 * 4 + 0] = t4[0] + bv; v[i2 * 4 + 1] = t4[1] + bv;
      v[i2 * 4 + 2] = t4[2] + bv; v[i2 * 4 + 3] = t4[3] + bv;
    }
    uint32_t a[16];
#pragma unroll
    for (int i = 0; i < 16; ++i) a[i] = rnau(v[i]);
    union { s16x8 s; uint32_t u[4]; } H0, H1;
#pragma unroll
    for (int j = 0; j < 4; ++j) {
      H0.u[j] = pk2(a[2 * j], a[2 * j + 1]);
      H1.u[j] = pk2(a[8 + 2 * j], a[8 + 2 * j + 1]);
    }
    const size_t off = ((size_t)((b * 8 + h) * HD + o)) * NPIX + n0 + nc;
    *(s16x8*)(d2 + off) = H0.s; *(s16x8*)(d2 + off + 8) = H1.s;
  }
}

__global__ __launch_bounds__(128) void gemm_qkv(
    const short* __restrict__ Wth, const short* __restrict__ Wtl,
    const float* __restrict__ q_b, const float* __restrict__ kv_b,
    const short* __restrict__ Xh, const short* __restrict__ Xl,
    const short* __restrict__ Ah, const short* __restrict__ Al,
    short* __restrict__ Qhi, short* __restrict__ Khi, short* __restrict__ Vhi,
    float qscale) {
  __shared__ __align__(16) float Cl[32][68];
  const int by = blockIdx.y;
  if (by < 8) {
    gemm_body(Wth, Wtl, q_b, Xh, Xl, nullptr, Qhi, nullptr,
              2, qscale, blockIdx.x * 64, by * 32, blockIdx.z, Cl);
  } else {
    gemm_body(Wth + 65536, Wtl + 65536, kv_b, Ah, Al, nullptr, Khi, Vhi,
              2, 1.0f, blockIdx.x * 64, (by - 8) * 32, blockIdx.z, Cl);
  }
}

__global__ __launch_bounds__(128) void gemm_proj(
    const short* __restrict__ Wh, const short* __restrict__ Wl,
    const float* __restrict__ bias,
    const short* __restrict__ Zh, const short* __restrict__ Zl,
    float* __restrict__ out) {
  __shared__ __align__(16) float Cl[32][68];
  gemm_body(Wh, Wl, bias, Zh, Zl, out, nullptr, nullptr,
            0, 1.0f, blockIdx.x * 64, blockIdx.y * 32, blockIdx.z, Cl);
}

// ---------------------------------------------------------------------------
// MFMA flash attention: no-max softmax, register-direct PV (K=16 MFMAs,
// B-operand == S C-layout, verified R6), lag-1 pipeline (verified R5):
//   iter t: load tile t+1 -> QK(tile t) -> PV(tile t-1) -> f_t = exp/pack
// Wave owns 32 q-rows (2 tiles) sharing one K/V stream. Zero LDS.
// ---------------------------------------------------------------------------
__global__ __launch_bounds__(256) void attn_mfma(
    const short* __restrict__ Qhi,   // [bh][n][32]
    const short* __restrict__ Khi,   // [bh][n][32]
    const short* __restrict__ Vhi,   // [bh][32][N]
    float* __restrict__ part_o,      // [row][NSPLIT][32]
    float* __restrict__ part_l) {    // [row][NSPLIT]
  const int sb = blockIdx.x;        // 0..287
  const int bh = sb / 18;
  const int qb = sb % 18;           // 128-row block
  const int split = blockIdx.y;     // 0..3
  const int tid = threadIdx.x;
  const int wave = tid >> 6, lane = tid & 63;
  const int g = lane >> 4, q = lane & 15;
  const int base = qb * 128 + wave * 32;

  const size_t qoff = ((size_t)bh * NPIX + base + q) * HD + g * 8;
  const s16x8 qhA = *(const s16x8*)(Qhi + qoff);
  const s16x8 qhB = *(const s16x8*)(Qhi + qoff + 16 * HD);

  const short* kp = Khi + ((size_t)bh * NPIX + split * KPS + q) * HD + g * 8;
  const short* vp = Vhi + ((size_t)bh * HD + q) * NPIX + split * KPS;

  const f32x4 Z4 = {0.f, 0.f, 0.f, 0.f};
  f32x4 OA0 = Z4, OA1 = Z4, OB0 = Z4, OB1 = Z4;
  f32x4 lva = Z4, lvb = Z4;

  s16x8 kb[2][2];
  s16x4 vb[2][4];
  s16x4 fA0, fA1, fB0, fB1;            // P frags of tile t (made at iter t)
  s16x4 w0, w1, w2, w3;                // V frags of tile t-1

  // tile 0 loads
  kb[0][0] = *(const s16x8*)(kp);
  kb[0][1] = *(const s16x8*)(kp + 16 * HD);
  vb[0][0] = *(const s16x4*)(vp + g * 4);
  vb[0][1] = *(const s16x4*)(vp + 16 + g * 4);
  vb[0][2] = *(const s16x4*)(vp + 16 * NPIX + g * 4);
  vb[0][3] = *(const s16x4*)(vp + 16 * NPIX + 16 + g * 4);

#pragma unroll
  for (int t = 0; t < KPS / KT; ++t) {
    const int cur = t & 1, nxt = cur ^ 1;
    if (t < KPS / KT - 1) {            // prefetch tile t+1 (consumed next iter)
      const short* kpt = kp + (t + 1) * (KT * HD);
      const short* vpt = vp + (t + 1) * KT;
      kb[nxt][0] = *(const s16x8*)(kpt);
      kb[nxt][1] = *(const s16x8*)(kpt + 16 * HD);
      vb[nxt][0] = *(const s16x4*)(vpt + g * 4);
      vb[nxt][1] = *(const s16x4*)(vpt + 16 + g * 4);
      vb[nxt][2] = *(const s16x4*)(vpt + 16 * NPIX + g * 4);
      vb[nxt][3] = *(const s16x4*)(vpt + 16 * NPIX + 16 + g * 4);
    }
    // QK for tile t (loads issued last iter -> latency covered)
    f32x4 SA0 = MFMA32(kb[cur][0], qhA, Z4);
    f32x4 SA1 = MFMA32(kb[cur][1], qhA, Z4);
    f32x4 SB0 = MFMA32(kb[cur][0], qhB, Z4);
    f32x4 SB1 = MFMA32(kb[cur][1], qhB, Z4);
    // PV for tile t-1: issues while S_t drains the MFMA pipe
    if (t > 0) {
      OA0 = MFMA16(w0, fA0, OA0); OA0 = MFMA16(w1, fA1, OA0);
      OA1 = MFMA16(w2, fA0, OA1); OA1 = MFMA16(w3, fA1, OA1);
      OB0 = MFMA16(w0, fB0, OB0); OB0 = MFMA16(w1, fB1, OB0);
      OB1 = MFMA16(w2, fB0, OB1); OB1 = MFMA16(w3, fB1, OB1);
    }
    // softmax weights for tile t
    f32x4 pA0, pA1, pB0, pB1;
#pragma unroll
    for (int r = 0; r < 4; ++r) {
      pA0[r] = exp2f(SA0[r]); pA1[r] = exp2f(SA1[r]);
      pB0[r] = exp2f(SB0[r]); pB1[r] = exp2f(SB1[r]);
    }
    lva += pA0 + pA1;
    lvb += pB0 + pB1;
    fA0 = pack_bf16x4(pA0); fA1 = pack_bf16x4(pA1);
    fB0 = pack_bf16x4(pB0); fB1 = pack_bf16x4(pB1);
    w0 = vb[cur][0]; w1 = vb[cur][1]; w2 = vb[cur][2]; w3 = vb[cur][3];
  }
  // epilogue PV for last tile
  OA0 = MFMA16(w0, fA0, OA0); OA0 = MFMA16(w1, fA1, OA0);
  OA1 = MFMA16(w2, fA0, OA1); OA1 = MFMA16(w3, fA1, OA1);
  OB0 = MFMA16(w0, fB0, OB0); OB0 = MFMA16(w1, fB1, OB0);
  OB1 = MFMA16(w2, fB0, OB1); OB1 = MFMA16(w3, fB1, OB1);

  float lA = (lva[0] + lva[1]) + (lva[2] + lva[3]);
  float lB = (lvb[0] + lvb[1]) + (lvb[2] + lvb[3]);
  lA += __shfl_xor(lA, 16); lA += __shfl_xor(lA, 32);
  lB += __shfl_xor(lB, 16); lB += __shfl_xor(lB, 32);

  const int rowA = bh * NPIX + base + q;
  const int rowB = rowA + 16;
  float* poA = part_o + ((size_t)rowA * NSPLIT + split) * HD;
  float* poB = part_o + ((size_t)rowB * NSPLIT + split) * HD;
  *(f32x4*)(poA + g * 4) = OA0;
  *(f32x4*)(poA + 16 + g * 4) = OA1;
  *(f32x4*)(poB + g * 4) = OB0;
  *(f32x4*)(poB + 16 + g * 4) = OB1;
  if (g == 0) {
    part_l[(size_t)rowA * NSPLIT + split] = lA;
    part_l[(size_t)rowB * NSPLIT + split] = lB;
  }
}

// ---------------------------------------------------------------------------
// Merge splits (plain sums) and emit SCRAMBLED z hi/lo [b][p][256]:
// p=(n%9)*256+head*32+dd, c=n/9.
// ---------------------------------------------------------------------------
__global__ __launch_bounds__(288) void attn_merge(const float* __restrict__ part_o,
                                                  const float* __restrict__ part_l,
                                                  short* __restrict__ zh,
                                                  short* __restrict__ zl) {
  const int blk = blockIdx.x;          // 128 = 16 bh * 8
  const int bh = blk >> 3;
  const int n0 = (blk & 7) * 288;
  const int head = bh & 7, b = bh >> 3;
  const int t = threadIdx.x;
  __shared__ __align__(16) float T[288][36];
  {
    const int idx = bh * NPIX + n0 + t;
    const float* pl = part_l + (size_t)idx * NSPLIT;
    float L = 0.f;
#pragma unroll
    for (int s = 0; s < NSPLIT; ++s) L += pl[s];
    const float inv = 1.f / L;
    const float* po = part_o + (size_t)idx * (NSPLIT * HD);
#pragma unroll
    for (int u = 0; u < 8; ++u) {
      f32x4 v = {0.f, 0.f, 0.f, 0.f};
#pragma unroll
      for (int s = 0; s < NSPLIT; ++s)
        v += *(const f32x4*)(po + s * HD + u * 4);
      v[0] *= inv; v[1] *= inv; v[2] *= inv; v[3] *= inv;
      *(f32x4*)&T[t][u * 4] = v;
    }
  }
  __syncthreads();
  {
    const int r9 = t / 32, dd = t & 31;
    const int p = r9 * 256 + head * HD + dd;
    const int c0 = n0 / 9;
    float v[32];
#pragma unroll
    for (int j = 0; j < 32; ++j) v[j] = T[9 * j + r9][dd];
    uint32_t a[32], al[32];
#pragma unroll
    for (int j = 0; j < 32; ++j) a[j] = rnau(v[j]);
#pragma unroll
    for (int j = 0; j < 32; ++j) al[j] = rnau(v[j] - hif(a[j]));
    const size_t off = ((size_t)b * NPIX + p) * DIMC + c0;
#pragma unroll
    for (int c8 = 0; c8 < 4; ++c8) {
      union { s16x8 s; uint32_t u[4]; } H, L;
#pragma unroll
      for (int j = 0; j < 4; ++j) {
        H.u[j] = pk2(a[c8 * 8 + 2 * j], a[c8 * 8 + 2 * j + 1]);
        L.u[j] = pk2(al[c8 * 8 + 2 * j], al[c8 * 8 + 2 * j + 1]);
      }
      *(s16x8*)(zh + off + c8 * 8) = H.s;
      *(s16x8*)(zl + off + c8 * 8) = L.s;
    }
  }
}

// ---------------------------------------------------------------------------
extern "C" void kernel_launch(void* const* d_in, const int* in_sizes, int n_in,
                              void* d_out, int out_size, void* d_ws, size_t ws_size,
                              hipStream_t stream) {
  const float* x      = (const float*)d_in[0];
  const float* q_w    = (const float*)d_in[1];
  const float* q_b    = (const float*)d_in[2];
  const float* kv_w   = (const float*)d_in[3];
  const float* kv_b   = (const float*)d_in[4];
  const float* proj_w = (const float*)d_in[5];
  const float* proj_b = (const float*)d_in[6];
  float* out = (float*)d_out;

  // Workspace (42.0 MB total; 43.6 MB proven available in R1).
  // [0, 28.3MB): prologue xavg/Xh/Xl/Ah/Al (14.2MB), then part_o.
  char* w = (char*)d_ws;
  float* xavg = (float*)w;                       // 4,718,592
  short* Xh   = (short*)(w + 4718592);
  short* Xl   = (short*)(w + 7077888);
  short* Ah   = (short*)(w + 9437184);
  short* Al   = (short*)(w + 11796480);          // ends 14,155,776
  float* part_o = (float*)w;                     // aliases above (18.9MB used)
  short* Wth  = (short*)(w + 28311552);          // 524,288
  short* Wtl  = (short*)(w + 28835840);
  short* Qhi  = (short*)(w + 29360128);          // 2,359,296
  short* Khi  = (short*)(w + 31719424);
  short* Vhi  = (short*)(w + 34078720);
  float* part_l = (float*)(w + 36438016);        // 589,824 used
  short* Zh   = (short*)(w + 37322752);
  short* Zl   = (short*)(w + 39682048);          // ends 42,041,344

  const float qscale = 0.17677669529663689f * 1.4426950408889634f; // d^-0.5*log2(e)

  pool_kernel<<<BATCH * DIMC, 256, 0, stream>>>(x, xavg);
  conv_all<<<704, 256, 0, stream>>>(x, xavg, q_w, kv_w, proj_w,
                                    Xh, Xl, Ah, Al, Wth, Wtl);
  gemm_qkv<<<dim3(36, 24, 2), 128, 0, stream>>>(Wth, Wtl, q_b, kv_b,
                                                Xh, Xl, Ah, Al,
                                                Qhi, Khi, Vhi, qscale);
  attn_mfma<<<dim3(288, NSPLIT), 256, 0, stream>>>(Qhi, Khi, Vhi, part_o, part_l);
  attn_merge<<<128, 288, 0, stream>>>(part_o, part_l, Zh, Zl);
  gemm_proj<<<dim3(36, 8, 2), 128, 0, stream>>>(Wth + 196608, Wtl + 196608, proj_b,
                                                Zh, Zl, out);
}

// Round 9
// 175.593 us; speedup vs baseline: 1.1250x; 1.1194x over previous
//
#include <hip/hip_runtime.h>
#include <hip/hip_bf16.h>
#include <cstdint>

// Problem constants
#define DIMC  256
#define NH    8
#define HD    32
#define NPIX  2304       // 48*48
#define BATCH 2
#define NSPLIT 6
#define KPS   384        // keys per split (2304/6)
#define KT    32

typedef short s16x8 __attribute__((ext_vector_type(8)));
typedef short s16x4 __attribute__((ext_vector_type(4)));
typedef float f32x4 __attribute__((ext_vector_type(4)));

#define MFMA32(A,B,C) __builtin_amdgcn_mfma_f32_16x16x32_bf16(A,B,C,0,0,0)

// RNA (round-to-nearest-away) bf16 helpers: 1 VALU each.
__device__ inline uint32_t rnau(float x) { return __float_as_uint(x) + 0x8000u; }
__device__ inline uint32_t pk2(uint32_t l_, uint32_t h_) {
  return __builtin_amdgcn_perm(h_, l_, 0x07060302u);
}
__device__ inline float hif(uint32_t a) { return __uint_as_float(a & 0xffff0000u); }

// ---------------------------------------------------------------------------
// Pool: x_avg = (x + box3/9 + box5/25 + box7/49)/4, zero-pad, include_pad
// ---------------------------------------------------------------------------
__global__ __launch_bounds__(256) void pool_kernel(const float* __restrict__ x,
                                                   float* __restrict__ xavg) {
  const int plane = blockIdx.x;
  const float* xp = x + (size_t)plane * NPIX;
  __shared__ float sx[NPIX];
  __shared__ float h3[NPIX], h5[NPIX], h7[NPIX];
  const int t = threadIdx.x;
#pragma unroll
  for (int r = 0; r < 9; ++r) sx[r * 256 + t] = xp[r * 256 + t];
  __syncthreads();
#pragma unroll
  for (int r = 0; r < 9; ++r) {
    int p = r * 256 + t;
    int i = p / 48, j = p - i * 48;
    float a3 = 0.f, a5 = 0.f, a7 = 0.f;
#pragma unroll
    for (int dj = -3; dj <= 3; ++dj) {
      int jj = j + dj;
      if (jj < 0 || jj >= 48) continue;
      float v = sx[i * 48 + jj];
      a7 += v;
      if (dj >= -2 && dj <= 2) a5 += v;
      if (dj >= -1 && dj <= 1) a3 += v;
    }
    h3[p] = a3; h5[p] = a5; h7[p] = a7;
  }
  __syncthreads();
#pragma unroll
  for (int r = 0; r < 9; ++r) {
    int p = r * 256 + t;
    int i = p / 48, j = p - i * 48;
    float b3 = 0.f, b5 = 0.f, b7 = 0.f;
#pragma unroll
    for (int di = -3; di <= 3; ++di) {
      int ii = i + di;
      if (ii < 0 || ii >= 48) continue;
      int q = ii * 48 + j;
      b7 += h7[q];
      if (di >= -2 && di <= 2) b5 += h5[q];
      if (di >= -1 && di <= 1) b3 += h3[q];
    }
    xavg[(size_t)plane * NPIX + p] =
        0.25f * (sx[p] + b3 * (1.f / 9.f) + b5 * (1.f / 25.f) + b7 * (1.f / 49.f));
  }
}

// ---------------------------------------------------------------------------
// Fused converts: blocks 0..287 tconv(x), 288..575 tconv(xavg), 576..703 wconv
// ---------------------------------------------------------------------------
__global__ __launch_bounds__(256) void conv_all(
    const float* __restrict__ x, const float* __restrict__ xavg,
    const float* __restrict__ qw, const float* __restrict__ kvw,
    const float* __restrict__ pw_,
    short* __restrict__ Xh, short* __restrict__ Xl,
    short* __restrict__ Ah, short* __restrict__ Al,
    short* __restrict__ Wth, short* __restrict__ Wtl) {
  const int bx = blockIdx.x;
  const int t = threadIdx.x;
  if (bx < 576) {
    const float* src = (bx < 288) ? x : xavg;
    short* dhi = (bx < 288) ? Xh : Ah;
    short* dlo = (bx < 288) ? Xl : Al;
    const int bb = (bx < 288) ? bx : bx - 288;
    const int n0 = (bb % 36) * 64, c0 = ((bb / 36) & 3) * 64, b = bb / 144;
    __shared__ __align__(16) float T[64][68];
    {
      const int c = t >> 2, n4 = (t & 3) * 16;
      const float* sp = src + ((size_t)b * DIMC + c0 + c) * NPIX + n0 + n4;
#pragma unroll
      for (int i2 = 0; i2 < 4; ++i2)
        *(f32x4*)&T[c][n4 + i2 * 4] = *(const f32x4*)(sp + i2 * 4);
    }
    __syncthreads();
    {
      const int n = t >> 2, c4 = (t & 3) * 16;
      float v[16];
#pragma unroll
      for (int i = 0; i < 16; ++i) v[i] = T[c4 + i][n];
      uint32_t a[16], al[16];
#pragma unroll
      for (int i = 0; i < 16; ++i) a[i] = rnau(v[i]);
#pragma unroll
      for (int i = 0; i < 16; ++i) al[i] = rnau(v[i] - hif(a[i]));
      union { s16x8 s; uint32_t u[4]; } H0, H1, L0, L1;
#pragma unroll
      for (int j = 0; j < 4; ++j) {
        H0.u[j] = pk2(a[2 * j], a[2 * j + 1]);
        H1.u[j] = pk2(a[8 + 2 * j], a[8 + 2 * j + 1]);
        L0.u[j] = pk2(al[2 * j], al[2 * j + 1]);
        L1.u[j] = pk2(al[8 + 2 * j], al[8 + 2 * j + 1]);
      }
      const size_t off = ((size_t)b * NPIX + n0 + n) * DIMC + c0 + c4;
      *(s16x8*)(dhi + off) = H0.s; *(s16x8*)(dhi + off + 8) = H1.s;
      *(s16x8*)(dlo + off) = L0.s; *(s16x8*)(dlo + off + 8) = L1.s;
    }
  } else {
    const int idx = ((bx - 576) * 256 + t) * 8;
    const float* s;
    int off;
    if (idx < 65536)       { s = qw;  off = idx; }
    else if (idx < 196608) { s = kvw; off = idx - 65536; }
    else                   { s = pw_; off = idx - 196608; }
    f32x4 x0 = *(const f32x4*)(s + off);
    f32x4 x1 = *(const f32x4*)(s + off + 4);
    float v[8] = {x0[0], x0[1], x0[2], x0[3], x1[0], x1[1], x1[2], x1[3]};
    uint32_t a[8], al[8];
#pragma unroll
    for (int i = 0; i < 8; ++i) a[i] = rnau(v[i]);
#pragma unroll
    for (int i = 0; i < 8; ++i) al[i] = rnau(v[i] - hif(a[i]));
    union { s16x8 s; uint32_t u[4]; } H, L;
#pragma unroll
    for (int j = 0; j < 4; ++j) {
      H.u[j] = pk2(a[2 * j], a[2 * j + 1]);
      L.u[j] = pk2(al[2 * j], al[2 * j + 1]);
    }
    *(s16x8*)(Wth + idx) = H.s;
    *(s16x8*)(Wtl + idx) = L.s;
  }
}

// ---------------------------------------------------------------------------
// GEMM body: Out[o][n] = sum_c W[o][c]*In[n][c] (+bias), hi/lo bf16, 3 MFMAs.
// ---------------------------------------------------------------------------
__device__ __forceinline__ void gemm_body(
    const short* __restrict__ Wh, const short* __restrict__ Wl,
    const float* __restrict__ bias,
    const short* __restrict__ Inh, const short* __restrict__ Inl,
    float* __restrict__ outf, short* __restrict__ d1, short* __restrict__ d2,
    int mode, float scale, int n0, int o0, int b, float (*Cl)[68]) {
  const int tid = threadIdx.x;
  const int wave = tid >> 6, lane = tid & 63;
  const int g = lane >> 4, q = lane & 15;

  const short* wph = Wh + ((o0 + wave * 16 + q) * DIMC + g * 8);
  const short* wpl = Wl + ((o0 + wave * 16 + q) * DIMC + g * 8);
  const short* iph = Inh + ((size_t)(b * NPIX + n0 + q) * DIMC + g * 8);
  const short* ipl = Inl + ((size_t)(b * NPIX + n0 + q) * DIMC + g * 8);

  f32x4 acc[4] = {{0,0,0,0},{0,0,0,0},{0,0,0,0},{0,0,0,0}};
#pragma unroll
  for (int c0 = 0; c0 < DIMC; c0 += 32) {
    s16x8 ah = *(const s16x8*)(wph + c0);
    s16x8 al = *(const s16x8*)(wpl + c0);
#pragma unroll
    for (int st = 0; st < 4; ++st) {
      s16x8 bh_ = *(const s16x8*)(iph + (size_t)st * 16 * DIMC + c0);
      s16x8 bl_ = *(const s16x8*)(ipl + (size_t)st * 16 * DIMC + c0);
      acc[st] = MFMA32(ah, bh_, acc[st]);
      acc[st] = MFMA32(ah, bl_, acc[st]);
      acc[st] = MFMA32(al, bh_, acc[st]);
    }
  }
#pragma unroll
  for (int st = 0; st < 4; ++st)
#pragma unroll
    for (int r = 0; r < 4; ++r)
      Cl[wave * 16 + g * 4 + r][st * 16 + q] = acc[st][r];
  __syncthreads();

  if (mode == 0) {
    const int o = tid >> 2, nc = (tid & 3) * 16;
    const float bv = bias[o0 + o];
    float* op = outf + ((size_t)b * DIMC + o0 + o) * NPIX + n0 + nc;
#pragma unroll
    for (int i2 = 0; i2 < 4; ++i2) {
      f32x4 v = *(const f32x4*)&Cl[o][nc + i2 * 4];
      v[0] += bv; v[1] += bv; v[2] += bv; v[3] += bv;
      *(f32x4*)(op + i2 * 4) = v;
    }
  } else if (o0 < 256) {
    // Q or K: (C+bias)*scale, hi-only, layout [bh][n][32]
    const int n = tid >> 1, oq = tid & 1;
    const int h = o0 >> 5;
    const float* bp = bias + o0 + oq * 16;
    float v[16];
#pragma unroll
    for (int i = 0; i < 16; ++i) v[i] = (Cl[oq * 16 + i][n] + bp[i]) * scale;
    uint32_t a[16];
#pragma unroll
    for (int i = 0; i < 16; ++i) a[i] = rnau(v[i]);
    union { s16x8 s; uint32_t u[4]; } H0, H1;
#pragma unroll
    for (int j = 0; j < 4; ++j) {
      H0.u[j] = pk2(a[2 * j], a[2 * j + 1]);
      H1.u[j] = pk2(a[8 + 2 * j], a[8 + 2 * j + 1]);
    }
    const size_t off = ((size_t)((b * 8 + h) * NPIX + n0 + n)) * HD + oq * 16;
    *(s16x8*)(d1 + off) = H0.s; *(s16x8*)(d1 + off + 8) = H1.s;
  } else {
    // V hi-only: dst [bh][d][n]
    const int o = tid >> 2, nc = (tid & 3) * 16;
    const int h = (o0 - 256) >> 5;
    const float bv = bias[o0 + o];
    float v[16];
#pragma unroll
    for (int i2 = 0; i2 < 4; ++i2) {
      f32x4 t4 = *(const f32x4*)&Cl[o][nc + i2 * 4];
      v[i2 * 4 + 0] = t4[0] + bv; v[i2 * 4 + 1] = t4[1] + bv;
      v[i2 * 4 + 2] = t4[2] + bv; v[i2 * 4 + 3] = t4[3] + bv;
    }
    uint32_t a[16];
#pragma unroll
    for (int i = 0; i < 16; ++i) a[i] = rnau(v[i]);
    union { s16x8 s; uint32_t u[4]; } H0, H1;
#pragma unroll
    for (int j = 0; j < 4; ++j) {
      H0.u[j] = pk2(a[2 * j], a[2 * j + 1]);
      H1.u[j] = pk2(a[8 + 2 * j], a[8 + 2 * j + 1]);
    }
    const size_t off = ((size_t)((b * 8 + h) * HD + o)) * NPIX + n0 + nc;
    *(s16x8*)(d2 + off) = H0.s; *(s16x8*)(d2 + off + 8) = H1.s;
  }
}

__global__ __launch_bounds__(128) void gemm_qkv(
    const short* __restrict__ Wth, const short* __restrict__ Wtl,
    const float* __restrict__ q_b, const float* __restrict__ kv_b,
    const short* __restrict__ Xh, const short* __restrict__ Xl,
    const short* __restrict__ Ah, const short* __restrict__ Al,
    short* __restrict__ Qhi, short* __restrict__ Khi, short* __restrict__ Vhi,
    float qscale) {
  __shared__ __align__(16) float Cl[32][68];
  const int by = blockIdx.y;
  if (by < 8) {
    gemm_body(Wth, Wtl, q_b, Xh, Xl, nullptr, Qhi, nullptr,
              2, qscale, blockIdx.x * 64, by * 32, blockIdx.z, Cl);
  } else {
    gemm_body(Wth + 65536, Wtl + 65536, kv_b, Ah, Al, nullptr, Khi, Vhi,
              2, 1.0f, blockIdx.x * 64, (by - 8) * 32, blockIdx.z, Cl);
  }
}

__global__ __launch_bounds__(128) void gemm_proj(
    const short* __restrict__ Wh, const short* __restrict__ Wl,
    const float* __restrict__ bias,
    const short* __restrict__ Zh, const short* __restrict__ Zl,
    float* __restrict__ out) {
  __shared__ __align__(16) float Cl[32][68];
  gemm_body(Wh, Wl, bias, Zh, Zl, out, nullptr, nullptr,
            0, 1.0f, blockIdx.x * 64, blockIdx.y * 32, blockIdx.z, Cl);
}

// ---------------------------------------------------------------------------
// MFMA flash attention — EXACT R5 structure (best measured per-wave
// throughput: 47us @ NSPLIT=4): no-max softmax, LDS P round-trip, lag-1
// pipeline, MFMA32 PV, wave owns 32 q-rows sharing one K/V stream.
// Only change: NSPLIT 4->6 for occupancy (R6-measured 38% at 1728 blocks).
// ---------------------------------------------------------------------------
__global__ __launch_bounds__(256) void attn_mfma(
    const short* __restrict__ Qhi,   // [bh][n][32]
    const short* __restrict__ Khi,   // [bh][n][32]
    const short* __restrict__ Vhi,   // [bh][32][N]
    float* __restrict__ part_o,      // [row][NSPLIT][32]
    float* __restrict__ part_l) {    // [row][NSPLIT]
  const int sb = blockIdx.x;        // 0..287
  const int bh = sb / 18;
  const int qb = sb % 18;           // 128-row block
  const int split = blockIdx.y;     // 0..NSPLIT-1
  const int tid = threadIdx.x;
  const int wave = tid >> 6, lane = tid & 63;
  const int g = lane >> 4, q = lane & 15;
  const int base = qb * 128 + wave * 32;

  __shared__ __align__(16) short Plds[4][2][16 * 40];
  short* pwA = &Plds[wave][0][0];
  short* pwB = &Plds[wave][1][0];

  const size_t qoff = ((size_t)bh * NPIX + base + q) * HD + g * 8;
  const s16x8 qhA = *(const s16x8*)(Qhi + qoff);
  const s16x8 qhB = *(const s16x8*)(Qhi + qoff + 16 * HD);

  const short* kp = Khi + ((size_t)bh * NPIX + split * KPS + q) * HD + g * 8;
  const short* vp = Vhi + ((size_t)bh * HD + q) * NPIX + split * KPS + g * 8;

  const f32x4 Z4 = {0.f, 0.f, 0.f, 0.f};
  f32x4 OA0 = Z4, OA1 = Z4, OB0 = Z4, OB1 = Z4;
  f32x4 lva = Z4, lvb = Z4;
  s16x8 kb[2][2], vb[2][2], pfA, pfB, vp0, vp1;

  kb[0][0] = *(const s16x8*)(kp);
  kb[0][1] = *(const s16x8*)(kp + 16 * HD);
  vb[0][0] = *(const s16x8*)(vp);
  vb[0][1] = *(const s16x8*)(vp + 16 * NPIX);

#pragma unroll
  for (int t = 0; t < KPS / KT; ++t) {
    const int cur = t & 1, nxt = cur ^ 1;
    if (t < KPS / KT - 1) {
      const short* kpn = kp + (t + 1) * (KT * HD);
      const short* vpn = vp + (t + 1) * KT;
      kb[nxt][0] = *(const s16x8*)(kpn);
      kb[nxt][1] = *(const s16x8*)(kpn + 16 * HD);
      vb[nxt][0] = *(const s16x8*)(vpn);
      vb[nxt][1] = *(const s16x8*)(vpn + 16 * NPIX);
    }
    f32x4 SA0 = MFMA32(kb[cur][0], qhA, Z4);
    f32x4 SA1 = MFMA32(kb[cur][1], qhA, Z4);
    f32x4 SB0 = MFMA32(kb[cur][0], qhB, Z4);
    f32x4 SB1 = MFMA32(kb[cur][1], qhB, Z4);
    if (t > 0) {   // PV for tile t-1 (pf read issued last iter)
      OA0 = MFMA32(vp0, pfA, OA0);
      OA1 = MFMA32(vp1, pfA, OA1);
      OB0 = MFMA32(vp0, pfB, OB0);
      OB1 = MFMA32(vp1, pfB, OB1);
    }
    {   // q-tile A softmax weights
      f32x4 p0, p1;
#pragma unroll
      for (int r = 0; r < 4; ++r) { p0[r] = exp2f(SA0[r]); p1[r] = exp2f(SA1[r]); }
      lva += p0 + p1;
      uint2 w0, w1;
      w0.x = pk2(rnau(p0[0]), rnau(p0[1])); w0.y = pk2(rnau(p0[2]), rnau(p0[3]));
      w1.x = pk2(rnau(p1[0]), rnau(p1[1])); w1.y = pk2(rnau(p1[2]), rnau(p1[3]));
      *(uint2*)&pwA[q * 40 + g * 4] = w0;
      *(uint2*)&pwA[q * 40 + 16 + g * 4] = w1;
    }
    {   // q-tile B
      f32x4 p0, p1;
#pragma unroll
      for (int r = 0; r < 4; ++r) { p0[r] = exp2f(SB0[r]); p1[r] = exp2f(SB1[r]); }
      lvb += p0 + p1;
      uint2 w0, w1;
      w0.x = pk2(rnau(p0[0]), rnau(p0[1])); w0.y = pk2(rnau(p0[2]), rnau(p0[3]));
      w1.x = pk2(rnau(p1[0]), rnau(p1[1])); w1.y = pk2(rnau(p1[2]), rnau(p1[3]));
      *(uint2*)&pwB[q * 40 + g * 4] = w0;
      *(uint2*)&pwB[q * 40 + 16 + g * 4] = w1;
    }
    vp0 = vb[cur][0]; vp1 = vb[cur][1];
    pfA = *(const s16x8*)&pwA[q * 40 + g * 8];   // consumed next iter
    pfB = *(const s16x8*)&pwB[q * 40 + g * 8];
  }
  // epilogue PV for last tile
  OA0 = MFMA32(vp0, pfA, OA0);
  OA1 = MFMA32(vp1, pfA, OA1);
  OB0 = MFMA32(vp0, pfB, OB0);
  OB1 = MFMA32(vp1, pfB, OB1);

  float lA = (lva[0] + lva[1]) + (lva[2] + lva[3]);
  float lB = (lvb[0] + lvb[1]) + (lvb[2] + lvb[3]);
  lA += __shfl_xor(lA, 16); lA += __shfl_xor(lA, 32);
  lB += __shfl_xor(lB, 16); lB += __shfl_xor(lB, 32);

  const int rowA = bh * NPIX + base + q;
  const int rowB = rowA + 16;
  float* poA = part_o + ((size_t)rowA * NSPLIT + split) * HD;
  float* poB = part_o + ((size_t)rowB * NSPLIT + split) * HD;
  *(f32x4*)(poA + g * 4) = OA0;
  *(f32x4*)(poA + 16 + g * 4) = OA1;
  *(f32x4*)(poB + g * 4) = OB0;
  *(f32x4*)(poB + 16 + g * 4) = OB1;
  if (g == 0) {
    part_l[(size_t)rowA * NSPLIT + split] = lA;
    part_l[(size_t)rowB * NSPLIT + split] = lB;
  }
}

// ---------------------------------------------------------------------------
// Merge splits, emit SCRAMBLED z hi/lo [b][p][256]. Now 256 blocks (was 128):
// block = (bh, chunk of 144 rows). Phase 1: row = t/2, half the u-range each.
// Phase 2: all 288 threads (r9 = t/32 in 0..8, dd = t&31), 16 channels.
// ---------------------------------------------------------------------------
__global__ __launch_bounds__(288) void attn_merge(const float* __restrict__ part_o,
                                                  const float* __restrict__ part_l,
                                                  short* __restrict__ zh,
                                                  short* __restrict__ zl) {
  const int blk = blockIdx.x;          // 256 = 16 bh * 16
  const int bh = blk >> 4;
  const int n0 = (blk & 15) * 144;
  const int head = bh & 7, b = bh >> 3;
  const int t = threadIdx.x;
  __shared__ __align__(16) float T[144][36];
  {
    const int r = t >> 1, uh = (t & 1) * 4;   // r in 0..143
    const int idx = bh * NPIX + n0 + r;
    const float* pl = part_l + (size_t)idx * NSPLIT;
    float L = 0.f;
#pragma unroll
    for (int s = 0; s < NSPLIT; ++s) L += pl[s];
    const float inv = 1.f / L;
    const float* po = part_o + (size_t)idx * (NSPLIT * HD);
#pragma unroll
    for (int u = 0; u < 4; ++u) {
      f32x4 v = {0.f, 0.f, 0.f, 0.f};
#pragma unroll
      for (int s = 0; s < NSPLIT; ++s)
        v += *(const f32x4*)(po + s * HD + (uh + u) * 4);
      v[0] *= inv; v[1] *= inv; v[2] *= inv; v[3] *= inv;
      *(f32x4*)&T[r][(uh + u) * 4] = v;
    }
  }
  __syncthreads();
  {
    const int r9 = t / 32, dd = t & 31;    // r9 in 0..8
    const int p = r9 * 256 + head * HD + dd;
    const int c0 = n0 / 9;                  // 16 channels per chunk
    float v[16];
#pragma unroll
    for (int j = 0; j < 16; ++j) v[j] = T[9 * j + r9][dd];
    uint32_t a[16], al[16];
#pragma unroll
    for (int j = 0; j < 16; ++j) a[j] = rnau(v[j]);
#pragma unroll
    for (int j = 0; j < 16; ++j) al[j] = rnau(v[j] - hif(a[j]));
    const size_t off = ((size_t)b * NPIX + p) * DIMC + c0;
#pragma unroll
    for (int c8 = 0; c8 < 2; ++c8) {
      union { s16x8 s; uint32_t u[4]; } H, L;
#pragma unroll
      for (int j = 0; j < 4; ++j) {
        H.u[j] = pk2(a[c8 * 8 + 2 * j], a[c8 * 8 + 2 * j + 1]);
        L.u[j] = pk2(al[c8 * 8 + 2 * j], al[c8 * 8 + 2 * j + 1]);
      }
      *(s16x8*)(zh + off + c8 * 8) = H.s;
      *(s16x8*)(zl + off + c8 * 8) = L.s;
    }
  }
}

// ---------------------------------------------------------------------------
extern "C" void kernel_launch(void* const* d_in, const int* in_sizes, int n_in,
                              void* d_out, int out_size, void* d_ws, size_t ws_size,
                              hipStream_t stream) {
  const float* x      = (const float*)d_in[0];
  const float* q_w    = (const float*)d_in[1];
  const float* q_b    = (const float*)d_in[2];
  const float* kv_w   = (const float*)d_in[3];
  const float* kv_b   = (const float*)d_in[4];
  const float* proj_w = (const float*)d_in[5];
  const float* proj_b = (const float*)d_in[6];
  float* out = (float*)d_out;

  // Workspace (42.0 MB; 43.6 MB proven available in R1).
  // [0, 28.3MB): prologue xavg/Xh/Xl/Ah/Al (14.2MB), then part_o (NSPLIT=6).
  char* w = (char*)d_ws;
  float* xavg = (float*)w;                       // 4,718,592
  short* Xh   = (short*)(w + 4718592);
  short* Xl   = (short*)(w + 7077888);
  short* Ah   = (short*)(w + 9437184);
  short* Al   = (short*)(w + 11796480);          // ends 14,155,776
  float* part_o = (float*)w;                     // 28,311,552 (aliases above)
  short* Wth  = (short*)(w + 28311552);          // 524,288
  short* Wtl  = (short*)(w + 28835840);
  short* Qhi  = (short*)(w + 29360128);          // 2,359,296
  short* Khi  = (short*)(w + 31719424);
  short* Vhi  = (short*)(w + 34078720);
  float* part_l = (float*)(w + 36438016);        // 884,736
  short* Zh   = (short*)(w + 37322752);
  short* Zl   = (short*)(w + 39682048);          // ends 42,041,344

  const float qscale = 0.17677669529663689f * 1.4426950408889634f; // d^-0.5*log2(e)

  pool_kernel<<<BATCH * DIMC, 256, 0, stream>>>(x, xavg);
  conv_all<<<704, 256, 0, stream>>>(x, xavg, q_w, kv_w, proj_w,
                                    Xh, Xl, Ah, Al, Wth, Wtl);
  gemm_qkv<<<dim3(36, 24, 2), 128, 0, stream>>>(Wth, Wtl, q_b, kv_b,
                                                Xh, Xl, Ah, Al,
                                                Qhi, Khi, Vhi, qscale);
  attn_mfma<<<dim3(288, NSPLIT), 256, 0, stream>>>(Qhi, Khi, Vhi, part_o, part_l);
  attn_merge<<<256, 288, 0, stream>>>(part_o, part_l, Zh, Zl);
  gemm_proj<<<dim3(36, 8, 2), 128, 0, stream>>>(Wth + 196608, Wtl + 196608, proj_b,
                                                Zh, Zl, out);
}

// Round 11
// 175.338 us; speedup vs baseline: 1.1266x; 1.0015x over previous
//
#include <hip/hip_runtime.h>
#include <hip/hip_bf16.h>
#include <cstdint>

// Problem constants
#define DIMC  256
#define NH    8
#define HD    32
#define NPIX  2304       // 48*48
#define BATCH 2
#define NSPLIT 6
#define KPS   384        // keys per split (2304/6)
#define KT    32

typedef short s16x8 __attribute__((ext_vector_type(8)));
typedef short s16x4 __attribute__((ext_vector_type(4)));
typedef float f32x4 __attribute__((ext_vector_type(4)));

#define MFMA32(A,B,C) __builtin_amdgcn_mfma_f32_16x16x32_bf16(A,B,C,0,0,0)

// RNA (round-to-nearest-away) bf16 helpers: 1 VALU each.
__device__ inline uint32_t rnau(float x) { return __float_as_uint(x) + 0x8000u; }
__device__ inline uint32_t pk2(uint32_t l_, uint32_t h_) {
  return __builtin_amdgcn_perm(h_, l_, 0x07060302u);
}
__device__ inline float hif(uint32_t a) { return __uint_as_float(a & 0xffff0000u); }

// ---------------------------------------------------------------------------
// Pool: x_avg = (x + box3/9 + box5/25 + box7/49)/4, zero-pad, include_pad
// ---------------------------------------------------------------------------
__global__ __launch_bounds__(256) void pool_kernel(const float* __restrict__ x,
                                                   float* __restrict__ xavg) {
  const int plane = blockIdx.x;
  const float* xp = x + (size_t)plane * NPIX;
  __shared__ float sx[NPIX];
  __shared__ float h3[NPIX], h5[NPIX], h7[NPIX];
  const int t = threadIdx.x;
#pragma unroll
  for (int r = 0; r < 9; ++r) sx[r * 256 + t] = xp[r * 256 + t];
  __syncthreads();
#pragma unroll
  for (int r = 0; r < 9; ++r) {
    int p = r * 256 + t;
    int i = p / 48, j = p - i * 48;
    float a3 = 0.f, a5 = 0.f, a7 = 0.f;
#pragma unroll
    for (int dj = -3; dj <= 3; ++dj) {
      int jj = j + dj;
      if (jj < 0 || jj >= 48) continue;
      float v = sx[i * 48 + jj];
      a7 += v;
      if (dj >= -2 && dj <= 2) a5 += v;
      if (dj >= -1 && dj <= 1) a3 += v;
    }
    h3[p] = a3; h5[p] = a5; h7[p] = a7;
  }
  __syncthreads();
#pragma unroll
  for (int r = 0; r < 9; ++r) {
    int p = r * 256 + t;
    int i = p / 48, j = p - i * 48;
    float b3 = 0.f, b5 = 0.f, b7 = 0.f;
#pragma unroll
    for (int di = -3; di <= 3; ++di) {
      int ii = i + di;
      if (ii < 0 || ii >= 48) continue;
      int q = ii * 48 + j;
      b7 += h7[q];
      if (di >= -2 && di <= 2) b5 += h5[q];
      if (di >= -1 && di <= 1) b3 += h3[q];
    }
    xavg[(size_t)plane * NPIX + p] =
        0.25f * (sx[p] + b3 * (1.f / 9.f) + b5 * (1.f / 25.f) + b7 * (1.f / 49.f));
  }
}

// ---------------------------------------------------------------------------
// Fused converts: blocks 0..287 tconv(x), 288..575 tconv(xavg), 576..703 wconv
// ---------------------------------------------------------------------------
__global__ __launch_bounds__(256) void conv_all(
    const float* __restrict__ x, const float* __restrict__ xavg,
    const float* __restrict__ qw, const float* __restrict__ kvw,
    const float* __restrict__ pw_,
    short* __restrict__ Xh, short* __restrict__ Xl,
    short* __restrict__ Ah, short* __restrict__ Al,
    short* __restrict__ Wth, short* __restrict__ Wtl) {
  const int bx = blockIdx.x;
  const int t = threadIdx.x;
  if (bx < 576) {
    const float* src = (bx < 288) ? x : xavg;
    short* dhi = (bx < 288) ? Xh : Ah;
    short* dlo = (bx < 288) ? Xl : Al;
    const int bb = (bx < 288) ? bx : bx - 288;
    const int n0 = (bb % 36) * 64, c0 = ((bb / 36) & 3) * 64, b = bb / 144;
    __shared__ __align__(16) float T[64][68];
    {
      const int c = t >> 2, n4 = (t & 3) * 16;
      const float* sp = src + ((size_t)b * DIMC + c0 + c) * NPIX + n0 + n4;
#pragma unroll
      for (int i2 = 0; i2 < 4; ++i2)
        *(f32x4*)&T[c][n4 + i2 * 4] = *(const f32x4*)(sp + i2 * 4);
    }
    __syncthreads();
    {
      const int n = t >> 2, c4 = (t & 3) * 16;
      float v[16];
#pragma unroll
      for (int i = 0; i < 16; ++i) v[i] = T[c4 + i][n];
      uint32_t a[16], al[16];
#pragma unroll
      for (int i = 0; i < 16; ++i) a[i] = rnau(v[i]);
#pragma unroll
      for (int i = 0; i < 16; ++i) al[i] = rnau(v[i] - hif(a[i]));
      union { s16x8 s; uint32_t u[4]; } H0, H1, L0, L1;
#pragma unroll
      for (int j = 0; j < 4; ++j) {
        H0.u[j] = pk2(a[2 * j], a[2 * j + 1]);
        H1.u[j] = pk2(a[8 + 2 * j], a[8 + 2 * j + 1]);
        L0.u[j] = pk2(al[2 * j], al[2 * j + 1]);
        L1.u[j] = pk2(al[8 + 2 * j], al[8 + 2 * j + 1]);
      }
      const size_t off = ((size_t)b * NPIX + n0 + n) * DIMC + c0 + c4;
      *(s16x8*)(dhi + off) = H0.s; *(s16x8*)(dhi + off + 8) = H1.s;
      *(s16x8*)(dlo + off) = L0.s; *(s16x8*)(dlo + off + 8) = L1.s;
    }
  } else {
    const int idx = ((bx - 576) * 256 + t) * 8;
    const float* s;
    int off;
    if (idx < 65536)       { s = qw;  off = idx; }
    else if (idx < 196608) { s = kvw; off = idx - 65536; }
    else                   { s = pw_; off = idx - 196608; }
    f32x4 x0 = *(const f32x4*)(s + off);
    f32x4 x1 = *(const f32x4*)(s + off + 4);
    float v[8] = {x0[0], x0[1], x0[2], x0[3], x1[0], x1[1], x1[2], x1[3]};
    uint32_t a[8], al[8];
#pragma unroll
    for (int i = 0; i < 8; ++i) a[i] = rnau(v[i]);
#pragma unroll
    for (int i = 0; i < 8; ++i) al[i] = rnau(v[i] - hif(a[i]));
    union { s16x8 s; uint32_t u[4]; } H, L;
#pragma unroll
    for (int j = 0; j < 4; ++j) {
      H.u[j] = pk2(a[2 * j], a[2 * j + 1]);
      L.u[j] = pk2(al[2 * j], al[2 * j + 1]);
    }
    *(s16x8*)(Wth + idx) = H.s;
    *(s16x8*)(Wtl + idx) = L.s;
  }
}

// ---------------------------------------------------------------------------
// GEMM body: Out[o][n] = sum_c W[o][c]*In[n][c] (+bias), hi/lo bf16, 3 MFMAs.
// ---------------------------------------------------------------------------
__device__ __forceinline__ void gemm_body(
    const short* __restrict__ Wh, const short* __restrict__ Wl,
    const float* __restrict__ bias,
    const short* __restrict__ Inh, const short* __restrict__ Inl,
    float* __restrict__ outf, short* __restrict__ d1, short* __restrict__ d2,
    int mode, float scale, int n0, int o0, int b, float (*Cl)[68]) {
  const int tid = threadIdx.x;
  const int wave = tid >> 6, lane = tid & 63;
  const int g = lane >> 4, q = lane & 15;

  const short* wph = Wh + ((o0 + wave * 16 + q) * DIMC + g * 8);
  const short* wpl = Wl + ((o0 + wave * 16 + q) * DIMC + g * 8);
  const short* iph = Inh + ((size_t)(b * NPIX + n0 + q) * DIMC + g * 8);
  const short* ipl = Inl + ((size_t)(b * NPIX + n0 + q) * DIMC + g * 8);

  f32x4 acc[4] = {{0,0,0,0},{0,0,0,0},{0,0,0,0},{0,0,0,0}};
#pragma unroll
  for (int c0 = 0; c0 < DIMC; c0 += 32) {
    s16x8 ah = *(const s16x8*)(wph + c0);
    s16x8 al = *(const s16x8*)(wpl + c0);
#pragma unroll
    for (int st = 0; st < 4; ++st) {
      s16x8 bh_ = *(const s16x8*)(iph + (size_t)st * 16 * DIMC + c0);
      s16x8 bl_ = *(const s16x8*)(ipl + (size_t)st * 16 * DIMC + c0);
      acc[st] = MFMA32(ah, bh_, acc[st]);
      acc[st] = MFMA32(ah, bl_, acc[st]);
      acc[st] = MFMA32(al, bh_, acc[st]);
    }
  }
#pragma unroll
  for (int st = 0; st < 4; ++st)
#pragma unroll
    for (int r = 0; r < 4; ++r)
      Cl[wave * 16 + g * 4 + r][st * 16 + q] = acc[st][r];
  __syncthreads();

  if (mode == 0) {
    const int o = tid >> 2, nc = (tid & 3) * 16;
    const float bv = bias[o0 + o];
    float* op = outf + ((size_t)b * DIMC + o0 + o) * NPIX + n0 + nc;
#pragma unroll
    for (int i2 = 0; i2 < 4; ++i2) {
      f32x4 v = *(const f32x4*)&Cl[o][nc + i2 * 4];
      v[0] += bv; v[1] += bv; v[2] += bv; v[3] += bv;
      *(f32x4*)(op + i2 * 4) = v;
    }
  } else if (o0 < 256) {
    // Q or K: (C+bias)*scale, hi-only, layout [bh][n][32]
    const int n = tid >> 1, oq = tid & 1;
    const int h = o0 >> 5;
    const float* bp = bias + o0 + oq * 16;
    float v[16];
#pragma unroll
    for (int i = 0; i < 16; ++i) v[i] = (Cl[oq * 16 + i][n] + bp[i]) * scale;
    uint32_t a[16];
#pragma unroll
    for (int i = 0; i < 16; ++i) a[i] = rnau(v[i]);
    union { s16x8 s; uint32_t u[4]; } H0, H1;
#pragma unroll
    for (int j = 0; j < 4; ++j) {
      H0.u[j] = pk2(a[2 * j], a[2 * j + 1]);
      H1.u[j] = pk2(a[8 + 2 * j], a[8 + 2 * j + 1]);
    }
    const size_t off = ((size_t)((b * 8 + h) * NPIX + n0 + n)) * HD + oq * 16;
    *(s16x8*)(d1 + off) = H0.s; *(s16x8*)(d1 + off + 8) = H1.s;
  } else {
    // V hi-only: dst [bh][d][n]
    const int o = tid >> 2, nc = (tid & 3) * 16;
    const int h = (o0 - 256) >> 5;
    const float bv = bias[o0 + o];
    float v[16];
#pragma unroll
    for (int i2 = 0; i2 < 4; ++i2) {
      f32x4 t4 = *(const f32x4*)&Cl[o][nc + i2 * 4];
      v[i2 * 4 + 0] = t4[0] + bv; v[i2 * 4 + 1] = t4[1] + bv;
      v[i2 * 4 + 2] = t4[2] + bv; v[i2 * 4 + 3] = t4[3] + bv;
    }
    uint32_t a[16];
#pragma unroll
    for (int i = 0; i < 16; ++i) a[i] = rnau(v[i]);
    union { s16x8 s; uint32_t u[4]; } H0, H1;
#pragma unroll
    for (int j = 0; j < 4; ++j) {
      H0.u[j] = pk2(a[2 * j], a[2 * j + 1]);
      H1.u[j] = pk2(a[8 + 2 * j], a[8 + 2 * j + 1]);
    }
    const size_t off = ((size_t)((b * 8 + h) * HD + o)) * NPIX + n0 + nc;
    *(s16x8*)(d2 + off) = H0.s; *(s16x8*)(d2 + off + 8) = H1.s;
  }
}

__global__ __launch_bounds__(128) void gemm_qkv(
    const short* __restrict__ Wth, const short* __restrict__ Wtl,
    const float* __restrict__ q_b, const float* __restrict__ kv_b,
    const short* __restrict__ Xh, const short* __restrict__ Xl,
    const short* __restrict__ Ah, const short* __restrict__ Al,
    short* __restrict__ Qhi, short* __restrict__ Khi, short* __restrict__ Vhi,
    float qscale) {
  __shared__ __align__(16) float Cl[32][68];
  const int by = blockIdx.y;
  if (by < 8) {
    gemm_body(Wth, Wtl, q_b, Xh, Xl, nullptr, Qhi, nullptr,
              2, qscale, blockIdx.x * 64, by * 32, blockIdx.z, Cl);
  } else {
    gemm_body(Wth + 65536, Wtl + 65536, kv_b, Ah, Al, nullptr, Khi, Vhi,
              2, 1.0f, blockIdx.x * 64, (by - 8) * 32, blockIdx.z, Cl);
  }
}

__global__ __launch_bounds__(128) void gemm_proj(
    const short* __restrict__ Wh, const short* __restrict__ Wl,
    const float* __restrict__ bias,
    const short* __restrict__ Zh, const short* __restrict__ Zl,
    float* __restrict__ out) {
  __shared__ __align__(16) float Cl[32][68];
  gemm_body(Wh, Wl, bias, Zh, Zl, out, nullptr, nullptr,
            0, 1.0f, blockIdx.x * 64, blockIdx.y * 32, blockIdx.z, Cl);
}

// ---------------------------------------------------------------------------
// MFMA flash attention — R5 structure + NSPLIT=6 (R9-measured best, <44us):
// no-max softmax, LDS P round-trip, lag-1 pipeline, MFMA32 PV,
// wave owns 32 q-rows sharing one K/V stream.
// ---------------------------------------------------------------------------
__global__ __launch_bounds__(256) void attn_mfma(
    const short* __restrict__ Qhi,   // [bh][n][32]
    const short* __restrict__ Khi,   // [bh][n][32]
    const short* __restrict__ Vhi,   // [bh][32][N]
    float* __restrict__ part_o,      // [row][NSPLIT][32]
    float* __restrict__ part_l) {    // [row][NSPLIT]
  const int sb = blockIdx.x;        // 0..287
  const int bh = sb / 18;
  const int qb = sb % 18;           // 128-row block
  const int split = blockIdx.y;     // 0..NSPLIT-1
  const int tid = threadIdx.x;
  const int wave = tid >> 6, lane = tid & 63;
  const int g = lane >> 4, q = lane & 15;
  const int base = qb * 128 + wave * 32;

  __shared__ __align__(16) short Plds[4][2][16 * 40];
  short* pwA = &Plds[wave][0][0];
  short* pwB = &Plds[wave][1][0];

  const size_t qoff = ((size_t)bh * NPIX + base + q) * HD + g * 8;
  const s16x8 qhA = *(const s16x8*)(Qhi + qoff);
  const s16x8 qhB = *(const s16x8*)(Qhi + qoff + 16 * HD);

  const short* kp = Khi + ((size_t)bh * NPIX + split * KPS + q) * HD + g * 8;
  const short* vp = Vhi + ((size_t)bh * HD + q) * NPIX + split * KPS + g * 8;

  const f32x4 Z4 = {0.f, 0.f, 0.f, 0.f};
  f32x4 OA0 = Z4, OA1 = Z4, OB0 = Z4, OB1 = Z4;
  f32x4 lva = Z4, lvb = Z4;
  s16x8 kb[2][2], vb[2][2], pfA, pfB, vp0, vp1;

  kb[0][0] = *(const s16x8*)(kp);
  kb[0][1] = *(const s16x8*)(kp + 16 * HD);
  vb[0][0] = *(const s16x8*)(vp);
  vb[0][1] = *(const s16x8*)(vp + 16 * NPIX);

#pragma unroll
  for (int t = 0; t < KPS / KT; ++t) {
    const int cur = t & 1, nxt = cur ^ 1;
    if (t < KPS / KT - 1) {
      const short* kpn = kp + (t + 1) * (KT * HD);
      const short* vpn = vp + (t + 1) * KT;
      kb[nxt][0] = *(const s16x8*)(kpn);
      kb[nxt][1] = *(const s16x8*)(kpn + 16 * HD);
      vb[nxt][0] = *(const s16x8*)(vpn);
      vb[nxt][1] = *(const s16x8*)(vpn + 16 * NPIX);
    }
    f32x4 SA0 = MFMA32(kb[cur][0], qhA, Z4);
    f32x4 SA1 = MFMA32(kb[cur][1], qhA, Z4);
    f32x4 SB0 = MFMA32(kb[cur][0], qhB, Z4);
    f32x4 SB1 = MFMA32(kb[cur][1], qhB, Z4);
    if (t > 0) {   // PV for tile t-1 (pf read issued last iter)
      OA0 = MFMA32(vp0, pfA, OA0);
      OA1 = MFMA32(vp1, pfA, OA1);
      OB0 = MFMA32(vp0, pfB, OB0);
      OB1 = MFMA32(vp1, pfB, OB1);
    }
    {   // q-tile A softmax weights
      f32x4 p0, p1;
#pragma unroll
      for (int r = 0; r < 4; ++r) { p0[r] = exp2f(SA0[r]); p1[r] = exp2f(SA1[r]); }
      lva += p0 + p1;
      uint2 w0, w1;
      w0.x = pk2(rnau(p0[0]), rnau(p0[1])); w0.y = pk2(rnau(p0[2]), rnau(p0[3]));
      w1.x = pk2(rnau(p1[0]), rnau(p1[1])); w1.y = pk2(rnau(p1[2]), rnau(p1[3]));
      *(uint2*)&pwA[q * 40 + g * 4] = w0;
      *(uint2*)&pwA[q * 40 + 16 + g * 4] = w1;
    }
    {   // q-tile B
      f32x4 p0, p1;
#pragma unroll
      for (int r = 0; r < 4; ++r) { p0[r] = exp2f(SB0[r]); p1[r] = exp2f(SB1[r]); }
      lvb += p0 + p1;
      uint2 w0, w1;
      w0.x = pk2(rnau(p0[0]), rnau(p0[1])); w0.y = pk2(rnau(p0[2]), rnau(p0[3]));
      w1.x = pk2(rnau(p1[0]), rnau(p1[1])); w1.y = pk2(rnau(p1[2]), rnau(p1[3]));
      *(uint2*)&pwB[q * 40 + g * 4] = w0;
      *(uint2*)&pwB[q * 40 + 16 + g * 4] = w1;
    }
    vp0 = vb[cur][0]; vp1 = vb[cur][1];
    pfA = *(const s16x8*)&pwA[q * 40 + g * 8];   // consumed next iter
    pfB = *(const s16x8*)&pwB[q * 40 + g * 8];
  }
  // epilogue PV for last tile
  OA0 = MFMA32(vp0, pfA, OA0);
  OA1 = MFMA32(vp1, pfA, OA1);
  OB0 = MFMA32(vp0, pfB, OB0);
  OB1 = MFMA32(vp1, pfB, OB1);

  float lA = (lva[0] + lva[1]) + (lva[2] + lva[3]);
  float lB = (lvb[0] + lvb[1]) + (lvb[2] + lvb[3]);
  lA += __shfl_xor(lA, 16); lA += __shfl_xor(lA, 32);
  lB += __shfl_xor(lB, 16); lB += __shfl_xor(lB, 32);

  const int rowA = bh * NPIX + base + q;
  const int rowB = rowA + 16;
  float* poA = part_o + ((size_t)rowA * NSPLIT + split) * HD;
  float* poB = part_o + ((size_t)rowB * NSPLIT + split) * HD;
  *(f32x4*)(poA + g * 4) = OA0;
  *(f32x4*)(poA + 16 + g * 4) = OA1;
  *(f32x4*)(poB + g * 4) = OB0;
  *(f32x4*)(poB + 16 + g * 4) = OB1;
  if (g == 0) {
    part_l[(size_t)rowA * NSPLIT + split] = lA;
    part_l[(size_t)rowB * NSPLIT + split] = lB;
  }
}

// ---------------------------------------------------------------------------
// Merge splits, emit SCRAMBLED z hi/lo [b][p][256]. 256 blocks.
// ---------------------------------------------------------------------------
__global__ __launch_bounds__(288) void attn_merge(const float* __restrict__ part_o,
                                                  const float* __restrict__ part_l,
                                                  short* __restrict__ zh,
                                                  short* __restrict__ zl) {
  const int blk = blockIdx.x;          // 256 = 16 bh * 16
  const int bh = blk >> 4;
  const int n0 = (blk & 15) * 144;
  const int head = bh & 7, b = bh >> 3;
  const int t = threadIdx.x;
  __shared__ __align__(16) float T[144][36];
  {
    const int r = t >> 1, uh = (t & 1) * 4;   // r in 0..143
    const int idx = bh * NPIX + n0 + r;
    const float* pl = part_l + (size_t)idx * NSPLIT;
    float L = 0.f;
#pragma unroll
    for (int s = 0; s < NSPLIT; ++s) L += pl[s];
    const float inv = 1.f / L;
    const float* po = part_o + (size_t)idx * (NSPLIT * HD);
#pragma unroll
    for (int u = 0; u < 4; ++u) {
      f32x4 v = {0.f, 0.f, 0.f, 0.f};
#pragma unroll
      for (int s = 0; s < NSPLIT; ++s)
        v += *(const f32x4*)(po + s * HD + (uh + u) * 4);
      v[0] *= inv; v[1] *= inv; v[2] *= inv; v[3] *= inv;
      *(f32x4*)&T[r][(uh + u) * 4] = v;
    }
  }
  __syncthreads();
  {
    const int r9 = t / 32, dd = t & 31;    // r9 in 0..8
    const int p = r9 * 256 + head * HD + dd;
    const int c0 = n0 / 9;                  // 16 channels per chunk
    float v[16];
#pragma unroll
    for (int j = 0; j < 16; ++j) v[j] = T[9 * j + r9][dd];
    uint32_t a[16], al[16];
#pragma unroll
    for (int j = 0; j < 16; ++j) a[j] = rnau(v[j]);
#pragma unroll
    for (int j = 0; j < 16; ++j) al[j] = rnau(v[j] - hif(a[j]));
    const size_t off = ((size_t)b * NPIX + p) * DIMC + c0;
#pragma unroll
    for (int c8 = 0; c8 < 2; ++c8) {
      union { s16x8 s; uint32_t u[4]; } H, L;
#pragma unroll
      for (int j = 0; j < 4; ++j) {
        H.u[j] = pk2(a[c8 * 8 + 2 * j], a[c8 * 8 + 2 * j + 1]);
        L.u[j] = pk2(al[c8 * 8 + 2 * j], al[c8 * 8 + 2 * j + 1]);
      }
      *(s16x8*)(zh + off + c8 * 8) = H.s;
      *(s16x8*)(zl + off + c8 * 8) = L.s;
    }
  }
}

// ---------------------------------------------------------------------------
extern "C" void kernel_launch(void* const* d_in, const int* in_sizes, int n_in,
                              void* d_out, int out_size, void* d_ws, size_t ws_size,
                              hipStream_t stream) {
  const float* x      = (const float*)d_in[0];
  const float* q_w    = (const float*)d_in[1];
  const float* q_b    = (const float*)d_in[2];
  const float* kv_w   = (const float*)d_in[3];
  const float* kv_b   = (const float*)d_in[4];
  const float* proj_w = (const float*)d_in[5];
  const float* proj_b = (const float*)d_in[6];
  float* out = (float*)d_out;

  // Workspace (42.0 MB; 43.6 MB proven available in R1).
  // [0, 28.3MB): prologue xavg/Xh/Xl/Ah/Al (14.2MB), then part_o (NSPLIT=6).
  char* w = (char*)d_ws;
  float* xavg = (float*)w;                       // 4,718,592
  short* Xh   = (short*)(w + 4718592);
  short* Xl   = (short*)(w + 7077888);
  short* Ah   = (short*)(w + 9437184);
  short* Al   = (short*)(w + 11796480);          // ends 14,155,776
  float* part_o = (float*)w;                     // 28,311,552 (aliases above)
  short* Wth  = (short*)(w + 28311552);          // 524,288
  short* Wtl  = (short*)(w + 28835840);
  short* Qhi  = (short*)(w + 29360128);          // 2,359,296
  short* Khi  = (short*)(w + 31719424);
  short* Vhi  = (short*)(w + 34078720);
  float* part_l = (float*)(w + 36438016);        // 884,736
  short* Zh   = (short*)(w + 37322752);
  short* Zl   = (short*)(w + 39682048);          // ends 42,041,344

  const float qscale = 0.17677669529663689f * 1.4426950408889634f; // d^-0.5*log2(e)

  pool_kernel<<<BATCH * DIMC, 256, 0, stream>>>(x, xavg);
  conv_all<<<704, 256, 0, stream>>>(x, xavg, q_w, kv_w, proj_w,
                                    Xh, Xl, Ah, Al, Wth, Wtl);
  gemm_qkv<<<dim3(36, 24, 2), 128, 0, stream>>>(Wth, Wtl, q_b, kv_b,
                                                Xh, Xl, Ah, Al,
                                                Qhi, Khi, Vhi, qscale);
  attn_mfma<<<dim3(288, NSPLIT), 256, 0, stream>>>(Qhi, Khi, Vhi, part_o, part_l);
  attn_merge<<<256, 288, 0, stream>>>(part_o, part_l, Zh, Zl);
  gemm_proj<<<dim3(36, 8, 2), 128, 0, stream>>>(Wth + 196608, Wtl + 196608, proj_b,
                                                Zh, Zl, out);
}

// Round 12
// 175.078 us; speedup vs baseline: 1.1283x; 1.0015x over previous
//
#include <hip/hip_runtime.h>
#include <hip/hip_bf16.h>
#include <cstdint>

// Problem constants
#define DIMC  256
#define NH    8
#define HD    32
#define NPIX  2304       // 48*48
#define BATCH 2
#define NSPLIT 6
#define KPS   384        // keys per split (2304/6)
#define KT    32

typedef short s16x8 __attribute__((ext_vector_type(8)));
typedef short s16x4 __attribute__((ext_vector_type(4)));
typedef float f32x4 __attribute__((ext_vector_type(4)));

#define MFMA32(A,B,C) __builtin_amdgcn_mfma_f32_16x16x32_bf16(A,B,C,0,0,0)

// RNA (round-to-nearest-away) bf16 helpers: 1 VALU each.
__device__ inline uint32_t rnau(float x) { return __float_as_uint(x) + 0x8000u; }
__device__ inline uint32_t pk2(uint32_t l_, uint32_t h_) {
  return __builtin_amdgcn_perm(h_, l_, 0x07060302u);
}
__device__ inline float hif(uint32_t a) { return __uint_as_float(a & 0xffff0000u); }

// ---------------------------------------------------------------------------
// Pool: x_avg = (x + box3/9 + box5/25 + box7/49)/4, zero-pad, include_pad
// ---------------------------------------------------------------------------
__global__ __launch_bounds__(256) void pool_kernel(const float* __restrict__ x,
                                                   float* __restrict__ xavg) {
  const int plane = blockIdx.x;
  const float* xp = x + (size_t)plane * NPIX;
  __shared__ float sx[NPIX];
  __shared__ float h3[NPIX], h5[NPIX], h7[NPIX];
  const int t = threadIdx.x;
#pragma unroll
  for (int r = 0; r < 9; ++r) sx[r * 256 + t] = xp[r * 256 + t];
  __syncthreads();
#pragma unroll
  for (int r = 0; r < 9; ++r) {
    int p = r * 256 + t;
    int i = p / 48, j = p - i * 48;
    float a3 = 0.f, a5 = 0.f, a7 = 0.f;
#pragma unroll
    for (int dj = -3; dj <= 3; ++dj) {
      int jj = j + dj;
      if (jj < 0 || jj >= 48) continue;
      float v = sx[i * 48 + jj];
      a7 += v;
      if (dj >= -2 && dj <= 2) a5 += v;
      if (dj >= -1 && dj <= 1) a3 += v;
    }
    h3[p] = a3; h5[p] = a5; h7[p] = a7;
  }
  __syncthreads();
#pragma unroll
  for (int r = 0; r < 9; ++r) {
    int p = r * 256 + t;
    int i = p / 48, j = p - i * 48;
    float b3 = 0.f, b5 = 0.f, b7 = 0.f;
#pragma unroll
    for (int di = -3; di <= 3; ++di) {
      int ii = i + di;
      if (ii < 0 || ii >= 48) continue;
      int q = ii * 48 + j;
      b7 += h7[q];
      if (di >= -2 && di <= 2) b5 += h5[q];
      if (di >= -1 && di <= 1) b3 += h3[q];
    }
    xavg[(size_t)plane * NPIX + p] =
        0.25f * (sx[p] + b3 * (1.f / 9.f) + b5 * (1.f / 25.f) + b7 * (1.f / 49.f));
  }
}

// ---------------------------------------------------------------------------
// Fused converts: blocks 0..287 tconv(x), 288..575 tconv(xavg), 576..703 wconv
// ---------------------------------------------------------------------------
__global__ __launch_bounds__(256) void conv_all(
    const float* __restrict__ x, const float* __restrict__ xavg,
    const float* __restrict__ qw, const float* __restrict__ kvw,
    const float* __restrict__ pw_,
    short* __restrict__ Xh, short* __restrict__ Xl,
    short* __restrict__ Ah, short* __restrict__ Al,
    short* __restrict__ Wth, short* __restrict__ Wtl) {
  const int bx = blockIdx.x;
  const int t = threadIdx.x;
  if (bx < 576) {
    const float* src = (bx < 288) ? x : xavg;
    short* dhi = (bx < 288) ? Xh : Ah;
    short* dlo = (bx < 288) ? Xl : Al;
    const int bb = (bx < 288) ? bx : bx - 288;
    const int n0 = (bb % 36) * 64, c0 = ((bb / 36) & 3) * 64, b = bb / 144;
    __shared__ __align__(16) float T[64][68];
    {
      const int c = t >> 2, n4 = (t & 3) * 16;
      const float* sp = src + ((size_t)b * DIMC + c0 + c) * NPIX + n0 + n4;
#pragma unroll
      for (int i2 = 0; i2 < 4; ++i2)
        *(f32x4*)&T[c][n4 + i2 * 4] = *(const f32x4*)(sp + i2 * 4);
    }
    __syncthreads();
    {
      const int n = t >> 2, c4 = (t & 3) * 16;
      float v[16];
#pragma unroll
      for (int i = 0; i < 16; ++i) v[i] = T[c4 + i][n];
      uint32_t a[16], al[16];
#pragma unroll
      for (int i = 0; i < 16; ++i) a[i] = rnau(v[i]);
#pragma unroll
      for (int i = 0; i < 16; ++i) al[i] = rnau(v[i] - hif(a[i]));
      union { s16x8 s; uint32_t u[4]; } H0, H1, L0, L1;
#pragma unroll
      for (int j = 0; j < 4; ++j) {
        H0.u[j] = pk2(a[2 * j], a[2 * j + 1]);
        H1.u[j] = pk2(a[8 + 2 * j], a[8 + 2 * j + 1]);
        L0.u[j] = pk2(al[2 * j], al[2 * j + 1]);
        L1.u[j] = pk2(al[8 + 2 * j], al[8 + 2 * j + 1]);
      }
      const size_t off = ((size_t)b * NPIX + n0 + n) * DIMC + c0 + c4;
      *(s16x8*)(dhi + off) = H0.s; *(s16x8*)(dhi + off + 8) = H1.s;
      *(s16x8*)(dlo + off) = L0.s; *(s16x8*)(dlo + off + 8) = L1.s;
    }
  } else {
    const int idx = ((bx - 576) * 256 + t) * 8;
    const float* s;
    int off;
    if (idx < 65536)       { s = qw;  off = idx; }
    else if (idx < 196608) { s = kvw; off = idx - 65536; }
    else                   { s = pw_; off = idx - 196608; }
    f32x4 x0 = *(const f32x4*)(s + off);
    f32x4 x1 = *(const f32x4*)(s + off + 4);
    float v[8] = {x0[0], x0[1], x0[2], x0[3], x1[0], x1[1], x1[2], x1[3]};
    uint32_t a[8], al[8];
#pragma unroll
    for (int i = 0; i < 8; ++i) a[i] = rnau(v[i]);
#pragma unroll
    for (int i = 0; i < 8; ++i) al[i] = rnau(v[i] - hif(a[i]));
    union { s16x8 s; uint32_t u[4]; } H, L;
#pragma unroll
    for (int j = 0; j < 4; ++j) {
      H.u[j] = pk2(a[2 * j], a[2 * j + 1]);
      L.u[j] = pk2(al[2 * j], al[2 * j + 1]);
    }
    *(s16x8*)(Wth + idx) = H.s;
    *(s16x8*)(Wtl + idx) = L.s;
  }
}

// ---------------------------------------------------------------------------
// GEMM body: Out[o][n] = sum_c W[o][c]*In[n][c] (+bias), hi/lo bf16, 3 MFMAs.
// ---------------------------------------------------------------------------
__device__ __forceinline__ void gemm_body(
    const short* __restrict__ Wh, const short* __restrict__ Wl,
    const float* __restrict__ bias,
    const short* __restrict__ Inh, const short* __restrict__ Inl,
    float* __restrict__ outf, short* __restrict__ d1, short* __restrict__ d2,
    int mode, float scale, int n0, int o0, int b, float (*Cl)[68]) {
  const int tid = threadIdx.x;
  const int wave = tid >> 6, lane = tid & 63;
  const int g = lane >> 4, q = lane & 15;

  const short* wph = Wh + ((o0 + wave * 16 + q) * DIMC + g * 8);
  const short* wpl = Wl + ((o0 + wave * 16 + q) * DIMC + g * 8);
  const short* iph = Inh + ((size_t)(b * NPIX + n0 + q) * DIMC + g * 8);
  const short* ipl = Inl + ((size_t)(b * NPIX + n0 + q) * DIMC + g * 8);

  f32x4 acc[4] = {{0,0,0,0},{0,0,0,0},{0,0,0,0},{0,0,0,0}};
#pragma unroll
  for (int c0 = 0; c0 < DIMC; c0 += 32) {
    s16x8 ah = *(const s16x8*)(wph + c0);
    s16x8 al = *(const s16x8*)(wpl + c0);
#pragma unroll
    for (int st = 0; st < 4; ++st) {
      s16x8 bh_ = *(const s16x8*)(iph + (size_t)st * 16 * DIMC + c0);
      s16x8 bl_ = *(const s16x8*)(ipl + (size_t)st * 16 * DIMC + c0);
      acc[st] = MFMA32(ah, bh_, acc[st]);
      acc[st] = MFMA32(ah, bl_, acc[st]);
      acc[st] = MFMA32(al, bh_, acc[st]);
    }
  }
#pragma unroll
  for (int st = 0; st < 4; ++st)
#pragma unroll
    for (int r = 0; r < 4; ++r)
      Cl[wave * 16 + g * 4 + r][st * 16 + q] = acc[st][r];
  __syncthreads();

  if (mode == 0) {
    const int o = tid >> 2, nc = (tid & 3) * 16;
    const float bv = bias[o0 + o];
    float* op = outf + ((size_t)b * DIMC + o0 + o) * NPIX + n0 + nc;
#pragma unroll
    for (int i2 = 0; i2 < 4; ++i2) {
      f32x4 v = *(const f32x4*)&Cl[o][nc + i2 * 4];
      v[0] += bv; v[1] += bv; v[2] += bv; v[3] += bv;
      *(f32x4*)(op + i2 * 4) = v;
    }
  } else if (o0 < 256) {
    // Q or K: (C+bias)*scale, hi-only, layout [bh][n][32]
    const int n = tid >> 1, oq = tid & 1;
    const int h = o0 >> 5;
    const float* bp = bias + o0 + oq * 16;
    float v[16];
#pragma unroll
    for (int i = 0; i < 16; ++i) v[i] = (Cl[oq * 16 + i][n] + bp[i]) * scale;
    uint32_t a[16];
#pragma unroll
    for (int i = 0; i < 16; ++i) a[i] = rnau(v[i]);
    union { s16x8 s; uint32_t u[4]; } H0, H1;
#pragma unroll
    for (int j = 0; j < 4; ++j) {
      H0.u[j] = pk2(a[2 * j], a[2 * j + 1]);
      H1.u[j] = pk2(a[8 + 2 * j], a[8 + 2 * j + 1]);
    }
    const size_t off = ((size_t)((b * 8 + h) * NPIX + n0 + n)) * HD + oq * 16;
    *(s16x8*)(d1 + off) = H0.s; *(s16x8*)(d1 + off + 8) = H1.s;
  } else {
    // V hi-only: dst [bh][d][n]
    const int o = tid >> 2, nc = (tid & 3) * 16;
    const int h = (o0 - 256) >> 5;
    const float bv = bias[o0 + o];
    float v[16];
#pragma unroll
    for (int i2 = 0; i2 < 4; ++i2) {
      f32x4 t4 = *(const f32x4*)&Cl[o][nc + i2 * 4];
      v[i2 * 4 + 0] = t4[0] + bv; v[i2 * 4 + 1] = t4[1] + bv;
      v[i2 * 4 + 2] = t4[2] + bv; v[i2 * 4 + 3] = t4[3] + bv;
    }
    uint32_t a[16];
#pragma unroll
    for (int i = 0; i < 16; ++i) a[i] = rnau(v[i]);
    union { s16x8 s; uint32_t u[4]; } H0, H1;
#pragma unroll
    for (int j = 0; j < 4; ++j) {
      H0.u[j] = pk2(a[2 * j], a[2 * j + 1]);
      H1.u[j] = pk2(a[8 + 2 * j], a[8 + 2 * j + 1]);
    }
    const size_t off = ((size_t)((b * 8 + h) * HD + o)) * NPIX + n0 + nc;
    *(s16x8*)(d2 + off) = H0.s; *(s16x8*)(d2 + off + 8) = H1.s;
  }
}

__global__ __launch_bounds__(128) void gemm_qkv(
    const short* __restrict__ Wth, const short* __restrict__ Wtl,
    const float* __restrict__ q_b, const float* __restrict__ kv_b,
    const short* __restrict__ Xh, const short* __restrict__ Xl,
    const short* __restrict__ Ah, const short* __restrict__ Al,
    short* __restrict__ Qhi, short* __restrict__ Khi, short* __restrict__ Vhi,
    float qscale) {
  __shared__ __align__(16) float Cl[32][68];
  const int by = blockIdx.y;
  if (by < 8) {
    gemm_body(Wth, Wtl, q_b, Xh, Xl, nullptr, Qhi, nullptr,
              2, qscale, blockIdx.x * 64, by * 32, blockIdx.z, Cl);
  } else {
    gemm_body(Wth + 65536, Wtl + 65536, kv_b, Ah, Al, nullptr, Khi, Vhi,
              2, 1.0f, blockIdx.x * 64, (by - 8) * 32, blockIdx.z, Cl);
  }
}

__global__ __launch_bounds__(128) void gemm_proj(
    const short* __restrict__ Wh, const short* __restrict__ Wl,
    const float* __restrict__ bias,
    const short* __restrict__ Zh, const short* __restrict__ Zl,
    float* __restrict__ out) {
  __shared__ __align__(16) float Cl[32][68];
  gemm_body(Wh, Wl, bias, Zh, Zl, out, nullptr, nullptr,
            0, 1.0f, blockIdx.x * 64, blockIdx.y * 32, blockIdx.z, Cl);
}

// ---------------------------------------------------------------------------
// MFMA flash attention — R5/R9 wave body, UNCHANGED math. Block split 256->128
// threads (2 waves, 64 q-rows/block): grid 3456 blocks for finer CU packing.
// Per-wave work/buffers byte-identical to R9 (no-max softmax, LDS P
// round-trip, lag-1 pipeline, MFMA32 PV, 32 q-rows/wave, one K/V stream).
// ---------------------------------------------------------------------------
__global__ __launch_bounds__(128) void attn_mfma(
    const short* __restrict__ Qhi,   // [bh][n][32]
    const short* __restrict__ Khi,   // [bh][n][32]
    const short* __restrict__ Vhi,   // [bh][32][N]
    float* __restrict__ part_o,      // [row][NSPLIT][32]
    float* __restrict__ part_l) {    // [row][NSPLIT]
  const int sb = blockIdx.x;        // 0..575 = 16 bh * 36 qb
  const int bh = sb / 36;
  const int qb = sb % 36;           // 64-row block
  const int split = blockIdx.y;     // 0..NSPLIT-1
  const int tid = threadIdx.x;
  const int wave = tid >> 6, lane = tid & 63;
  const int g = lane >> 4, q = lane & 15;
  const int base = qb * 64 + wave * 32;

  __shared__ __align__(16) short Plds[2][2][16 * 40];
  short* pwA = &Plds[wave][0][0];
  short* pwB = &Plds[wave][1][0];

  const size_t qoff = ((size_t)bh * NPIX + base + q) * HD + g * 8;
  const s16x8 qhA = *(const s16x8*)(Qhi + qoff);
  const s16x8 qhB = *(const s16x8*)(Qhi + qoff + 16 * HD);

  const short* kp = Khi + ((size_t)bh * NPIX + split * KPS + q) * HD + g * 8;
  const short* vp = Vhi + ((size_t)bh * HD + q) * NPIX + split * KPS + g * 8;

  const f32x4 Z4 = {0.f, 0.f, 0.f, 0.f};
  f32x4 OA0 = Z4, OA1 = Z4, OB0 = Z4, OB1 = Z4;
  f32x4 lva = Z4, lvb = Z4;
  s16x8 kb[2][2], vb[2][2], pfA, pfB, vp0, vp1;

  kb[0][0] = *(const s16x8*)(kp);
  kb[0][1] = *(const s16x8*)(kp + 16 * HD);
  vb[0][0] = *(const s16x8*)(vp);
  vb[0][1] = *(const s16x8*)(vp + 16 * NPIX);

#pragma unroll
  for (int t = 0; t < KPS / KT; ++t) {
    const int cur = t & 1, nxt = cur ^ 1;
    if (t < KPS / KT - 1) {
      const short* kpn = kp + (t + 1) * (KT * HD);
      const short* vpn = vp + (t + 1) * KT;
      kb[nxt][0] = *(const s16x8*)(kpn);
      kb[nxt][1] = *(const s16x8*)(kpn + 16 * HD);
      vb[nxt][0] = *(const s16x8*)(vpn);
      vb[nxt][1] = *(const s16x8*)(vpn + 16 * NPIX);
    }
    f32x4 SA0 = MFMA32(kb[cur][0], qhA, Z4);
    f32x4 SA1 = MFMA32(kb[cur][1], qhA, Z4);
    f32x4 SB0 = MFMA32(kb[cur][0], qhB, Z4);
    f32x4 SB1 = MFMA32(kb[cur][1], qhB, Z4);
    if (t > 0) {   // PV for tile t-1 (pf read issued last iter)
      OA0 = MFMA32(vp0, pfA, OA0);
      OA1 = MFMA32(vp1, pfA, OA1);
      OB0 = MFMA32(vp0, pfB, OB0);
      OB1 = MFMA32(vp1, pfB, OB1);
    }
    {   // q-tile A softmax weights
      f32x4 p0, p1;
#pragma unroll
      for (int r = 0; r < 4; ++r) { p0[r] = exp2f(SA0[r]); p1[r] = exp2f(SA1[r]); }
      lva += p0 + p1;
      uint2 w0, w1;
      w0.x = pk2(rnau(p0[0]), rnau(p0[1])); w0.y = pk2(rnau(p0[2]), rnau(p0[3]));
      w1.x = pk2(rnau(p1[0]), rnau(p1[1])); w1.y = pk2(rnau(p1[2]), rnau(p1[3]));
      *(uint2*)&pwA[q * 40 + g * 4] = w0;
      *(uint2*)&pwA[q * 40 + 16 + g * 4] = w1;
    }
    {   // q-tile B
      f32x4 p0, p1;
#pragma unroll
      for (int r = 0; r < 4; ++r) { p0[r] = exp2f(SB0[r]); p1[r] = exp2f(SB1[r]); }
      lvb += p0 + p1;
      uint2 w0, w1;
      w0.x = pk2(rnau(p0[0]), rnau(p0[1])); w0.y = pk2(rnau(p0[2]), rnau(p0[3]));
      w1.x = pk2(rnau(p1[0]), rnau(p1[1])); w1.y = pk2(rnau(p1[2]), rnau(p1[3]));
      *(uint2*)&pwB[q * 40 + g * 4] = w0;
      *(uint2*)&pwB[q * 40 + 16 + g * 4] = w1;
    }
    vp0 = vb[cur][0]; vp1 = vb[cur][1];
    pfA = *(const s16x8*)&pwA[q * 40 + g * 8];   // consumed next iter
    pfB = *(const s16x8*)&pwB[q * 40 + g * 8];
  }
  // epilogue PV for last tile
  OA0 = MFMA32(vp0, pfA, OA0);
  OA1 = MFMA32(vp1, pfA, OA1);
  OB0 = MFMA32(vp0, pfB, OB0);
  OB1 = MFMA32(vp1, pfB, OB1);

  float lA = (lva[0] + lva[1]) + (lva[2] + lva[3]);
  float lB = (lvb[0] + lvb[1]) + (lvb[2] + lvb[3]);
  lA += __shfl_xor(lA, 16); lA += __shfl_xor(lA, 32);
  lB += __shfl_xor(lB, 16); lB += __shfl_xor(lB, 32);

  const int rowA = bh * NPIX + base + q;
  const int rowB = rowA + 16;
  float* poA = part_o + ((size_t)rowA * NSPLIT + split) * HD;
  float* poB = part_o + ((size_t)rowB * NSPLIT + split) * HD;
  *(f32x4*)(poA + g * 4) = OA0;
  *(f32x4*)(poA + 16 + g * 4) = OA1;
  *(f32x4*)(poB + g * 4) = OB0;
  *(f32x4*)(poB + 16 + g * 4) = OB1;
  if (g == 0) {
    part_l[(size_t)rowA * NSPLIT + split] = lA;
    part_l[(size_t)rowB * NSPLIT + split] = lB;
  }
}

// ---------------------------------------------------------------------------
// Merge splits, emit SCRAMBLED z hi/lo [b][p][256]. 256 blocks.
// ---------------------------------------------------------------------------
__global__ __launch_bounds__(288) void attn_merge(const float* __restrict__ part_o,
                                                  const float* __restrict__ part_l,
                                                  short* __restrict__ zh,
                                                  short* __restrict__ zl) {
  const int blk = blockIdx.x;          // 256 = 16 bh * 16
  const int bh = blk >> 4;
  const int n0 = (blk & 15) * 144;
  const int head = bh & 7, b = bh >> 3;
  const int t = threadIdx.x;
  __shared__ __align__(16) float T[144][36];
  {
    const int r = t >> 1, uh = (t & 1) * 4;   // r in 0..143
    const int idx = bh * NPIX + n0 + r;
    const float* pl = part_l + (size_t)idx * NSPLIT;
    float L = 0.f;
#pragma unroll
    for (int s = 0; s < NSPLIT; ++s) L += pl[s];
    const float inv = 1.f / L;
    const float* po = part_o + (size_t)idx * (NSPLIT * HD);
#pragma unroll
    for (int u = 0; u < 4; ++u) {
      f32x4 v = {0.f, 0.f, 0.f, 0.f};
#pragma unroll
      for (int s = 0; s < NSPLIT; ++s)
        v += *(const f32x4*)(po + s * HD + (uh + u) * 4);
      v[0] *= inv; v[1] *= inv; v[2] *= inv; v[3] *= inv;
      *(f32x4*)&T[r][(uh + u) * 4] = v;
    }
  }
  __syncthreads();
  {
    const int r9 = t / 32, dd = t & 31;    // r9 in 0..8
    const int p = r9 * 256 + head * HD + dd;
    const int c0 = n0 / 9;                  // 16 channels per chunk
    float v[16];
#pragma unroll
    for (int j = 0; j < 16; ++j) v[j] = T[9 * j + r9][dd];
    uint32_t a[16], al[16];
#pragma unroll
    for (int j = 0; j < 16; ++j) a[j] = rnau(v[j]);
#pragma unroll
    for (int j = 0; j < 16; ++j) al[j] = rnau(v[j] - hif(a[j]));
    const size_t off = ((size_t)b * NPIX + p) * DIMC + c0;
#pragma unroll
    for (int c8 = 0; c8 < 2; ++c8) {
      union { s16x8 s; uint32_t u[4]; } H, L;
#pragma unroll
      for (int j = 0; j < 4; ++j) {
        H.u[j] = pk2(a[c8 * 8 + 2 * j], a[c8 * 8 + 2 * j + 1]);
        L.u[j] = pk2(al[c8 * 8 + 2 * j], al[c8 * 8 + 2 * j + 1]);
      }
      *(s16x8*)(zh + off + c8 * 8) = H.s;
      *(s16x8*)(zl + off + c8 * 8) = L.s;
    }
  }
}

// ---------------------------------------------------------------------------
extern "C" void kernel_launch(void* const* d_in, const int* in_sizes, int n_in,
                              void* d_out, int out_size, void* d_ws, size_t ws_size,
                              hipStream_t stream) {
  const float* x      = (const float*)d_in[0];
  const float* q_w    = (const float*)d_in[1];
  const float* q_b    = (const float*)d_in[2];
  const float* kv_w   = (const float*)d_in[3];
  const float* kv_b   = (const float*)d_in[4];
  const float* proj_w = (const float*)d_in[5];
  const float* proj_b = (const float*)d_in[6];
  float* out = (float*)d_out;

  // Workspace (42.0 MB; 43.6 MB proven available in R1).
  // [0, 28.3MB): prologue xavg/Xh/Xl/Ah/Al (14.2MB), then part_o (NSPLIT=6).
  char* w = (char*)d_ws;
  float* xavg = (float*)w;                       // 4,718,592
  short* Xh   = (short*)(w + 4718592);
  short* Xl   = (short*)(w + 7077888);
  short* Ah   = (short*)(w + 9437184);
  short* Al   = (short*)(w + 11796480);          // ends 14,155,776
  float* part_o = (float*)w;                     // 28,311,552 (aliases above)
  short* Wth  = (short*)(w + 28311552);          // 524,288
  short* Wtl  = (short*)(w + 28835840);
  short* Qhi  = (short*)(w + 29360128);          // 2,359,296
  short* Khi  = (short*)(w + 31719424);
  short* Vhi  = (short*)(w + 34078720);
  float* part_l = (float*)(w + 36438016);        // 884,736
  short* Zh   = (short*)(w + 37322752);
  short* Zl   = (short*)(w + 39682048);          // ends 42,041,344

  const float qscale = 0.17677669529663689f * 1.4426950408889634f; // d^-0.5*log2(e)

  pool_kernel<<<BATCH * DIMC, 256, 0, stream>>>(x, xavg);
  conv_all<<<704, 256, 0, stream>>>(x, xavg, q_w, kv_w, proj_w,
                                    Xh, Xl, Ah, Al, Wth, Wtl);
  gemm_qkv<<<dim3(36, 24, 2), 128, 0, stream>>>(Wth, Wtl, q_b, kv_b,
                                                Xh, Xl, Ah, Al,
                                                Qhi, Khi, Vhi, qscale);
  attn_mfma<<<dim3(16 * 36, NSPLIT), 128, 0, stream>>>(Qhi, Khi, Vhi, part_o, part_l);
  attn_merge<<<256, 288, 0, stream>>>(part_o, part_l, Zh, Zl);
  gemm_proj<<<dim3(36, 8, 2), 128, 0, stream>>>(Wth + 196608, Wtl + 196608, proj_b,
                                                Zh, Zl, out);
}

// Round 13
// 164.540 us; speedup vs baseline: 1.2005x; 1.0640x over previous
//
#include <hip/hip_runtime.h>
#include <hip/hip_bf16.h>
#include <cstdint>

// Problem constants
#define DIMC  256
#define NH    8
#define HD    32
#define NPIX  2304       // 48*48
#define BATCH 2
#define NSPLIT 6
#define KPS   384        // keys per split (2304/6)
#define KT    32

typedef short s16x8 __attribute__((ext_vector_type(8)));
typedef short s16x4 __attribute__((ext_vector_type(4)));
typedef float f32x4 __attribute__((ext_vector_type(4)));

#define MFMA32(A,B,C) __builtin_amdgcn_mfma_f32_16x16x32_bf16(A,B,C,0,0,0)

// RNA (round-to-nearest-away) bf16 helpers: 1 VALU each.
__device__ inline uint32_t rnau(float x) { return __float_as_uint(x) + 0x8000u; }
__device__ inline uint32_t pk2(uint32_t l_, uint32_t h_) {
  return __builtin_amdgcn_perm(h_, l_, 0x07060302u);
}
__device__ inline float hif(uint32_t a) { return __uint_as_float(a & 0xffff0000u); }

// ---------------------------------------------------------------------------
// Pool: x_avg = (x + box3/9 + box5/25 + box7/49)/4, zero-pad, include_pad
// ---------------------------------------------------------------------------
__global__ __launch_bounds__(256) void pool_kernel(const float* __restrict__ x,
                                                   float* __restrict__ xavg) {
  const int plane = blockIdx.x;
  const float* xp = x + (size_t)plane * NPIX;
  __shared__ float sx[NPIX];
  __shared__ float h3[NPIX], h5[NPIX], h7[NPIX];
  const int t = threadIdx.x;
#pragma unroll
  for (int r = 0; r < 9; ++r) sx[r * 256 + t] = xp[r * 256 + t];
  __syncthreads();
#pragma unroll
  for (int r = 0; r < 9; ++r) {
    int p = r * 256 + t;
    int i = p / 48, j = p - i * 48;
    float a3 = 0.f, a5 = 0.f, a7 = 0.f;
#pragma unroll
    for (int dj = -3; dj <= 3; ++dj) {
      int jj = j + dj;
      if (jj < 0 || jj >= 48) continue;
      float v = sx[i * 48 + jj];
      a7 += v;
      if (dj >= -2 && dj <= 2) a5 += v;
      if (dj >= -1 && dj <= 1) a3 += v;
    }
    h3[p] = a3; h5[p] = a5; h7[p] = a7;
  }
  __syncthreads();
#pragma unroll
  for (int r = 0; r < 9; ++r) {
    int p = r * 256 + t;
    int i = p / 48, j = p - i * 48;
    float b3 = 0.f, b5 = 0.f, b7 = 0.f;
#pragma unroll
    for (int di = -3; di <= 3; ++di) {
      int ii = i + di;
      if (ii < 0 || ii >= 48) continue;
      int q = ii * 48 + j;
      b7 += h7[q];
      if (di >= -2 && di <= 2) b5 += h5[q];
      if (di >= -1 && di <= 1) b3 += h3[q];
    }
    xavg[(size_t)plane * NPIX + p] =
        0.25f * (sx[p] + b3 * (1.f / 9.f) + b5 * (1.f / 25.f) + b7 * (1.f / 49.f));
  }
}

// ---------------------------------------------------------------------------
// Fused converts: blocks 0..287 tconv(x), 288..575 tconv(xavg), 576..703 wconv
// UNCHANGED from R11 (Xl/Al still produced; unused by the new QKV gemm —
// controlled experiment isolating the gemm change).
// ---------------------------------------------------------------------------
__global__ __launch_bounds__(256) void conv_all(
    const float* __restrict__ x, const float* __restrict__ xavg,
    const float* __restrict__ qw, const float* __restrict__ kvw,
    const float* __restrict__ pw_,
    short* __restrict__ Xh, short* __restrict__ Xl,
    short* __restrict__ Ah, short* __restrict__ Al,
    short* __restrict__ Wth, short* __restrict__ Wtl) {
  const int bx = blockIdx.x;
  const int t = threadIdx.x;
  if (bx < 576) {
    const float* src = (bx < 288) ? x : xavg;
    short* dhi = (bx < 288) ? Xh : Ah;
    short* dlo = (bx < 288) ? Xl : Al;
    const int bb = (bx < 288) ? bx : bx - 288;
    const int n0 = (bb % 36) * 64, c0 = ((bb / 36) & 3) * 64, b = bb / 144;
    __shared__ __align__(16) float T[64][68];
    {
      const int c = t >> 2, n4 = (t & 3) * 16;
      const float* sp = src + ((size_t)b * DIMC + c0 + c) * NPIX + n0 + n4;
#pragma unroll
      for (int i2 = 0; i2 < 4; ++i2)
        *(f32x4*)&T[c][n4 + i2 * 4] = *(const f32x4*)(sp + i2 * 4);
    }
    __syncthreads();
    {
      const int n = t >> 2, c4 = (t & 3) * 16;
      float v[16];
#pragma unroll
      for (int i = 0; i < 16; ++i) v[i] = T[c4 + i][n];
      uint32_t a[16], al[16];
#pragma unroll
      for (int i = 0; i < 16; ++i) a[i] = rnau(v[i]);
#pragma unroll
      for (int i = 0; i < 16; ++i) al[i] = rnau(v[i] - hif(a[i]));
      union { s16x8 s; uint32_t u[4]; } H0, H1, L0, L1;
#pragma unroll
      for (int j = 0; j < 4; ++j) {
        H0.u[j] = pk2(a[2 * j], a[2 * j + 1]);
        H1.u[j] = pk2(a[8 + 2 * j], a[8 + 2 * j + 1]);
        L0.u[j] = pk2(al[2 * j], al[2 * j + 1]);
        L1.u[j] = pk2(al[8 + 2 * j], al[8 + 2 * j + 1]);
      }
      const size_t off = ((size_t)b * NPIX + n0 + n) * DIMC + c0 + c4;
      *(s16x8*)(dhi + off) = H0.s; *(s16x8*)(dhi + off + 8) = H1.s;
      *(s16x8*)(dlo + off) = L0.s; *(s16x8*)(dlo + off + 8) = L1.s;
    }
  } else {
    const int idx = ((bx - 576) * 256 + t) * 8;
    const float* s;
    int off;
    if (idx < 65536)       { s = qw;  off = idx; }
    else if (idx < 196608) { s = kvw; off = idx - 65536; }
    else                   { s = pw_; off = idx - 196608; }
    f32x4 x0 = *(const f32x4*)(s + off);
    f32x4 x1 = *(const f32x4*)(s + off + 4);
    float v[8] = {x0[0], x0[1], x0[2], x0[3], x1[0], x1[1], x1[2], x1[3]};
    uint32_t a[8], al[8];
#pragma unroll
    for (int i = 0; i < 8; ++i) a[i] = rnau(v[i]);
#pragma unroll
    for (int i = 0; i < 8; ++i) al[i] = rnau(v[i] - hif(a[i]));
    union { s16x8 s; uint32_t u[4]; } H, L;
#pragma unroll
    for (int j = 0; j < 4; ++j) {
      H.u[j] = pk2(a[2 * j], a[2 * j + 1]);
      L.u[j] = pk2(al[2 * j], al[2 * j + 1]);
    }
    *(s16x8*)(Wth + idx) = H.s;
    *(s16x8*)(Wtl + idx) = L.s;
  }
}

// ---------------------------------------------------------------------------
// GEMM body (proj only): 3 MFMAs hi/lo. UNCHANGED from R11.
// ---------------------------------------------------------------------------
__device__ __forceinline__ void gemm_body(
    const short* __restrict__ Wh, const short* __restrict__ Wl,
    const float* __restrict__ bias,
    const short* __restrict__ Inh, const short* __restrict__ Inl,
    float* __restrict__ outf,
    int n0, int o0, int b, float (*Cl)[68]) {
  const int tid = threadIdx.x;
  const int wave = tid >> 6, lane = tid & 63;
  const int g = lane >> 4, q = lane & 15;

  const short* wph = Wh + ((o0 + wave * 16 + q) * DIMC + g * 8);
  const short* wpl = Wl + ((o0 + wave * 16 + q) * DIMC + g * 8);
  const short* iph = Inh + ((size_t)(b * NPIX + n0 + q) * DIMC + g * 8);
  const short* ipl = Inl + ((size_t)(b * NPIX + n0 + q) * DIMC + g * 8);

  f32x4 acc[4] = {{0,0,0,0},{0,0,0,0},{0,0,0,0},{0,0,0,0}};
#pragma unroll
  for (int c0 = 0; c0 < DIMC; c0 += 32) {
    s16x8 ah = *(const s16x8*)(wph + c0);
    s16x8 al = *(const s16x8*)(wpl + c0);
#pragma unroll
    for (int st = 0; st < 4; ++st) {
      s16x8 bh_ = *(const s16x8*)(iph + (size_t)st * 16 * DIMC + c0);
      s16x8 bl_ = *(const s16x8*)(ipl + (size_t)st * 16 * DIMC + c0);
      acc[st] = MFMA32(ah, bh_, acc[st]);
      acc[st] = MFMA32(ah, bl_, acc[st]);
      acc[st] = MFMA32(al, bh_, acc[st]);
    }
  }
#pragma unroll
  for (int st = 0; st < 4; ++st)
#pragma unroll
    for (int r = 0; r < 4; ++r)
      Cl[wave * 16 + g * 4 + r][st * 16 + q] = acc[st][r];
  __syncthreads();

  const int o = tid >> 2, nc = (tid & 3) * 16;
  const float bv = bias[o0 + o];
  float* op = outf + ((size_t)b * DIMC + o0 + o) * NPIX + n0 + nc;
#pragma unroll
  for (int i2 = 0; i2 < 4; ++i2) {
    f32x4 v = *(const f32x4*)&Cl[o][nc + i2 * 4];
    v[0] += bv; v[1] += bv; v[2] += bv; v[3] += bv;
    *(f32x4*)(op + i2 * 4) = v;
  }
}

__global__ __launch_bounds__(128) void gemm_proj(
    const short* __restrict__ Wh, const short* __restrict__ Wl,
    const float* __restrict__ bias,
    const short* __restrict__ Zh, const short* __restrict__ Zl,
    float* __restrict__ out) {
  __shared__ __align__(16) float Cl[32][68];
  gemm_body(Wh, Wl, bias, Zh, Zl, out,
            blockIdx.x * 64, blockIdx.y * 32, blockIdx.z, Cl);
}

// ---------------------------------------------------------------------------
// QKV GEMM, fully specialized: inputs HI-ONLY, 2 MFMAs (w_hi*x_hi + w_lo*x_hi).
// No nullable pointers, no runtime branch in the MFMA loop (isolates R10's
// suspected codegen hazard). by 0..7 -> Q (scaled); 8..23 -> KV.
// Epilogues copied verbatim from the R11 gemm_body mode-2 paths.
// ---------------------------------------------------------------------------
__global__ __launch_bounds__(128) void gemm_qkv_hi(
    const short* __restrict__ Wth, const short* __restrict__ Wtl,
    const float* __restrict__ q_b, const float* __restrict__ kv_b,
    const short* __restrict__ Xh, const short* __restrict__ Ah,
    short* __restrict__ Qhi, short* __restrict__ Khi, short* __restrict__ Vhi,
    float qscale) {
  __shared__ __align__(16) float Cl[32][68];
  const int by = blockIdx.y;
  const bool isQ = (by < 8);
  const int o0 = isQ ? by * 32 : (by - 8) * 32;
  const short* Wh = isQ ? Wth : Wth + 65536;
  const short* Wl = isQ ? Wtl : Wtl + 65536;
  const float* bias = isQ ? q_b : kv_b;
  const short* Inh = isQ ? Xh : Ah;
  const float scale = isQ ? qscale : 1.0f;
  short* d1 = isQ ? Qhi : Khi;   // used when o0 < 256 (Q or K)
  const int n0 = blockIdx.x * 64;
  const int b  = blockIdx.z;

  const int tid = threadIdx.x;
  const int wave = tid >> 6, lane = tid & 63;
  const int g = lane >> 4, q = lane & 15;

  const short* wph = Wh + ((o0 + wave * 16 + q) * DIMC + g * 8);
  const short* wpl = Wl + ((o0 + wave * 16 + q) * DIMC + g * 8);
  const short* iph = Inh + ((size_t)(b * NPIX + n0 + q) * DIMC + g * 8);

  f32x4 acc[4] = {{0,0,0,0},{0,0,0,0},{0,0,0,0},{0,0,0,0}};
#pragma unroll
  for (int c0 = 0; c0 < DIMC; c0 += 32) {
    s16x8 ah = *(const s16x8*)(wph + c0);
    s16x8 al = *(const s16x8*)(wpl + c0);
#pragma unroll
    for (int st = 0; st < 4; ++st) {
      s16x8 bh_ = *(const s16x8*)(iph + (size_t)st * 16 * DIMC + c0);
      acc[st] = MFMA32(ah, bh_, acc[st]);
      acc[st] = MFMA32(al, bh_, acc[st]);
    }
  }
#pragma unroll
  for (int st = 0; st < 4; ++st)
#pragma unroll
    for (int r = 0; r < 4; ++r)
      Cl[wave * 16 + g * 4 + r][st * 16 + q] = acc[st][r];
  __syncthreads();

  if (o0 < 256) {
    // Q or K: (C+bias)*scale, hi-only, layout [bh][n][32]
    const int n = tid >> 1, oq = tid & 1;
    const int h = o0 >> 5;
    const float* bp = bias + o0 + oq * 16;
    float v[16];
#pragma unroll
    for (int i = 0; i < 16; ++i) v[i] = (Cl[oq * 16 + i][n] + bp[i]) * scale;
    uint32_t a[16];
#pragma unroll
    for (int i = 0; i < 16; ++i) a[i] = rnau(v[i]);
    union { s16x8 s; uint32_t u[4]; } H0, H1;
#pragma unroll
    for (int j = 0; j < 4; ++j) {
      H0.u[j] = pk2(a[2 * j], a[2 * j + 1]);
      H1.u[j] = pk2(a[8 + 2 * j], a[8 + 2 * j + 1]);
    }
    const size_t off = ((size_t)((b * 8 + h) * NPIX + n0 + n)) * HD + oq * 16;
    *(s16x8*)(d1 + off) = H0.s; *(s16x8*)(d1 + off + 8) = H1.s;
  } else {
    // V hi-only: dst [bh][d][n]
    const int o = tid >> 2, nc = (tid & 3) * 16;
    const int h = (o0 - 256) >> 5;
    const float bv = bias[o0 + o];
    float v[16];
#pragma unroll
    for (int i2 = 0; i2 < 4; ++i2) {
      f32x4 t4 = *(const f32x4*)&Cl[o][nc + i2 * 4];
      v[i2 * 4 + 0] = t4[0] + bv; v[i2 * 4 + 1] = t4[1] + bv;
      v[i2 * 4 + 2] = t4[2] + bv; v[i2 * 4 + 3] = t4[3] + bv;
    }
    uint32_t a[16];
#pragma unroll
    for (int i = 0; i < 16; ++i) a[i] = rnau(v[i]);
    union { s16x8 s; uint32_t u[4]; } H0, H1;
#pragma unroll
    for (int j = 0; j < 4; ++j) {
      H0.u[j] = pk2(a[2 * j], a[2 * j + 1]);
      H1.u[j] = pk2(a[8 + 2 * j], a[8 + 2 * j + 1]);
    }
    const size_t off = ((size_t)((b * 8 + h) * HD + o)) * NPIX + n0 + nc;
    *(s16x8*)(Vhi + off) = H0.s; *(s16x8*)(Vhi + off + 8) = H1.s;
  }
}

// ---------------------------------------------------------------------------
// MFMA flash attention — R12 config (128 threads, 2 waves, 3456 blocks).
// UNCHANGED math: no-max softmax, LDS P round-trip, lag-1 pipeline, MFMA32 PV.
// ---------------------------------------------------------------------------
__global__ __launch_bounds__(128) void attn_mfma(
    const short* __restrict__ Qhi,   // [bh][n][32]
    const short* __restrict__ Khi,   // [bh][n][32]
    const short* __restrict__ Vhi,   // [bh][32][N]
    float* __restrict__ part_o,      // [row][NSPLIT][32]
    float* __restrict__ part_l) {    // [row][NSPLIT]
  const int sb = blockIdx.x;        // 0..575 = 16 bh * 36 qb
  const int bh = sb / 36;
  const int qb = sb % 36;           // 64-row block
  const int split = blockIdx.y;     // 0..NSPLIT-1
  const int tid = threadIdx.x;
  const int wave = tid >> 6, lane = tid & 63;
  const int g = lane >> 4, q = lane & 15;
  const int base = qb * 64 + wave * 32;

  __shared__ __align__(16) short Plds[2][2][16 * 40];
  short* pwA = &Plds[wave][0][0];
  short* pwB = &Plds[wave][1][0];

  const size_t qoff = ((size_t)bh * NPIX + base + q) * HD + g * 8;
  const s16x8 qhA = *(const s16x8*)(Qhi + qoff);
  const s16x8 qhB = *(const s16x8*)(Qhi + qoff + 16 * HD);

  const short* kp = Khi + ((size_t)bh * NPIX + split * KPS + q) * HD + g * 8;
  const short* vp = Vhi + ((size_t)bh * HD + q) * NPIX + split * KPS + g * 8;

  const f32x4 Z4 = {0.f, 0.f, 0.f, 0.f};
  f32x4 OA0 = Z4, OA1 = Z4, OB0 = Z4, OB1 = Z4;
  f32x4 lva = Z4, lvb = Z4;
  s16x8 kb[2][2], vb[2][2], pfA, pfB, vp0, vp1;

  kb[0][0] = *(const s16x8*)(kp);
  kb[0][1] = *(const s16x8*)(kp + 16 * HD);
  vb[0][0] = *(const s16x8*)(vp);
  vb[0][1] = *(const s16x8*)(vp + 16 * NPIX);

#pragma unroll
  for (int t = 0; t < KPS / KT; ++t) {
    const int cur = t & 1, nxt = cur ^ 1;
    if (t < KPS / KT - 1) {
      const short* kpn = kp + (t + 1) * (KT * HD);
      const short* vpn = vp + (t + 1) * KT;
      kb[nxt][0] = *(const s16x8*)(kpn);
      kb[nxt][1] = *(const s16x8*)(kpn + 16 * HD);
      vb[nxt][0] = *(const s16x8*)(vpn);
      vb[nxt][1] = *(const s16x8*)(vpn + 16 * NPIX);
    }
    f32x4 SA0 = MFMA32(kb[cur][0], qhA, Z4);
    f32x4 SA1 = MFMA32(kb[cur][1], qhA, Z4);
    f32x4 SB0 = MFMA32(kb[cur][0], qhB, Z4);
    f32x4 SB1 = MFMA32(kb[cur][1], qhB, Z4);
    if (t > 0) {   // PV for tile t-1 (pf read issued last iter)
      OA0 = MFMA32(vp0, pfA, OA0);
      OA1 = MFMA32(vp1, pfA, OA1);
      OB0 = MFMA32(vp0, pfB, OB0);
      OB1 = MFMA32(vp1, pfB, OB1);
    }
    {   // q-tile A softmax weights
      f32x4 p0, p1;
#pragma unroll
      for (int r = 0; r < 4; ++r) { p0[r] = exp2f(SA0[r]); p1[r] = exp2f(SA1[r]); }
      lva += p0 + p1;
      uint2 w0, w1;
      w0.x = pk2(rnau(p0[0]), rnau(p0[1])); w0.y = pk2(rnau(p0[2]), rnau(p0[3]));
      w1.x = pk2(rnau(p1[0]), rnau(p1[1])); w1.y = pk2(rnau(p1[2]), rnau(p1[3]));
      *(uint2*)&pwA[q * 40 + g * 4] = w0;
      *(uint2*)&pwA[q * 40 + 16 + g * 4] = w1;
    }
    {   // q-tile B
      f32x4 p0, p1;
#pragma unroll
      for (int r = 0; r < 4; ++r) { p0[r] = exp2f(SB0[r]); p1[r] = exp2f(SB1[r]); }
      lvb += p0 + p1;
      uint2 w0, w1;
      w0.x = pk2(rnau(p0[0]), rnau(p0[1])); w0.y = pk2(rnau(p0[2]), rnau(p0[3]));
      w1.x = pk2(rnau(p1[0]), rnau(p1[1])); w1.y = pk2(rnau(p1[2]), rnau(p1[3]));
      *(uint2*)&pwB[q * 40 + g * 4] = w0;
      *(uint2*)&pwB[q * 40 + 16 + g * 4] = w1;
    }
    vp0 = vb[cur][0]; vp1 = vb[cur][1];
    pfA = *(const s16x8*)&pwA[q * 40 + g * 8];   // consumed next iter
    pfB = *(const s16x8*)&pwB[q * 40 + g * 8];
  }
  // epilogue PV for last tile
  OA0 = MFMA32(vp0, pfA, OA0);
  OA1 = MFMA32(vp1, pfA, OA1);
  OB0 = MFMA32(vp0, pfB, OB0);
  OB1 = MFMA32(vp1, pfB, OB1);

  float lA = (lva[0] + lva[1]) + (lva[2] + lva[3]);
  float lB = (lvb[0] + lvb[1]) + (lvb[2] + lvb[3]);
  lA += __shfl_xor(lA, 16); lA += __shfl_xor(lA, 32);
  lB += __shfl_xor(lB, 16); lB += __shfl_xor(lB, 32);

  const int rowA = bh * NPIX + base + q;
  const int rowB = rowA + 16;
  float* poA = part_o + ((size_t)rowA * NSPLIT + split) * HD;
  float* poB = part_o + ((size_t)rowB * NSPLIT + split) * HD;
  *(f32x4*)(poA + g * 4) = OA0;
  *(f32x4*)(poA + 16 + g * 4) = OA1;
  *(f32x4*)(poB + g * 4) = OB0;
  *(f32x4*)(poB + 16 + g * 4) = OB1;
  if (g == 0) {
    part_l[(size_t)rowA * NSPLIT + split] = lA;
    part_l[(size_t)rowB * NSPLIT + split] = lB;
  }
}

// ---------------------------------------------------------------------------
// Merge splits, emit SCRAMBLED z hi/lo [b][p][256]. 256 blocks. UNCHANGED.
// ---------------------------------------------------------------------------
__global__ __launch_bounds__(288) void attn_merge(const float* __restrict__ part_o,
                                                  const float* __restrict__ part_l,
                                                  short* __restrict__ zh,
                                                  short* __restrict__ zl) {
  const int blk = blockIdx.x;          // 256 = 16 bh * 16
  const int bh = blk >> 4;
  const int n0 = (blk & 15) * 144;
  const int head = bh & 7, b = bh >> 3;
  const int t = threadIdx.x;
  __shared__ __align__(16) float T[144][36];
  {
    const int r = t >> 1, uh = (t & 1) * 4;   // r in 0..143
    const int idx = bh * NPIX + n0 + r;
    const float* pl = part_l + (size_t)idx * NSPLIT;
    float L = 0.f;
#pragma unroll
    for (int s = 0; s < NSPLIT; ++s) L += pl[s];
    const float inv = 1.f / L;
    const float* po = part_o + (size_t)idx * (NSPLIT * HD);
#pragma unroll
    for (int u = 0; u < 4; ++u) {
      f32x4 v = {0.f, 0.f, 0.f, 0.f};
#pragma unroll
      for (int s = 0; s < NSPLIT; ++s)
        v += *(const f32x4*)(po + s * HD + (uh + u) * 4);
      v[0] *= inv; v[1] *= inv; v[2] *= inv; v[3] *= inv;
      *(f32x4*)&T[r][(uh + u) * 4] = v;
    }
  }
  __syncthreads();
  {
    const int r9 = t / 32, dd = t & 31;    // r9 in 0..8
    const int p = r9 * 256 + head * HD + dd;
    const int c0 = n0 / 9;                  // 16 channels per chunk
    float v[16];
#pragma unroll
    for (int j = 0; j < 16; ++j) v[j] = T[9 * j + r9][dd];
    uint32_t a[16], al[16];
#pragma unroll
    for (int j = 0; j < 16; ++j) a[j] = rnau(v[j]);
#pragma unroll
    for (int j = 0; j < 16; ++j) al[j] = rnau(v[j] - hif(a[j]));
    const size_t off = ((size_t)b * NPIX + p) * DIMC + c0;
#pragma unroll
    for (int c8 = 0; c8 < 2; ++c8) {
      union { s16x8 s; uint32_t u[4]; } H, L;
#pragma unroll
      for (int j = 0; j < 4; ++j) {
        H.u[j] = pk2(a[c8 * 8 + 2 * j], a[c8 * 8 + 2 * j + 1]);
        L.u[j] = pk2(al[c8 * 8 + 2 * j], al[c8 * 8 + 2 * j + 1]);
      }
      *(s16x8*)(zh + off + c8 * 8) = H.s;
      *(s16x8*)(zl + off + c8 * 8) = L.s;
    }
  }
}

// ---------------------------------------------------------------------------
extern "C" void kernel_launch(void* const* d_in, const int* in_sizes, int n_in,
                              void* d_out, int out_size, void* d_ws, size_t ws_size,
                              hipStream_t stream) {
  const float* x      = (const float*)d_in[0];
  const float* q_w    = (const float*)d_in[1];
  const float* q_b    = (const float*)d_in[2];
  const float* kv_w   = (const float*)d_in[3];
  const float* kv_b   = (const float*)d_in[4];
  const float* proj_w = (const float*)d_in[5];
  const float* proj_b = (const float*)d_in[6];
  float* out = (float*)d_out;

  // Workspace (42.0 MB; 43.6 MB proven available in R1). Same layout as R11.
  char* w = (char*)d_ws;
  float* xavg = (float*)w;                       // 4,718,592
  short* Xh   = (short*)(w + 4718592);
  short* Xl   = (short*)(w + 7077888);
  short* Ah   = (short*)(w + 9437184);
  short* Al   = (short*)(w + 11796480);          // ends 14,155,776
  float* part_o = (float*)w;                     // 28,311,552 (aliases above)
  short* Wth  = (short*)(w + 28311552);          // 524,288
  short* Wtl  = (short*)(w + 28835840);
  short* Qhi  = (short*)(w + 29360128);          // 2,359,296
  short* Khi  = (short*)(w + 31719424);
  short* Vhi  = (short*)(w + 34078720);
  float* part_l = (float*)(w + 36438016);        // 884,736
  short* Zh   = (short*)(w + 37322752);
  short* Zl   = (short*)(w + 39682048);          // ends 42,041,344

  const float qscale = 0.17677669529663689f * 1.4426950408889634f; // d^-0.5*log2(e)

  pool_kernel<<<BATCH * DIMC, 256, 0, stream>>>(x, xavg);
  conv_all<<<704, 256, 0, stream>>>(x, xavg, q_w, kv_w, proj_w,
                                    Xh, Xl, Ah, Al, Wth, Wtl);
  gemm_qkv_hi<<<dim3(36, 24, 2), 128, 0, stream>>>(Wth, Wtl, q_b, kv_b,
                                                   Xh, Ah, Qhi, Khi, Vhi, qscale);
  attn_mfma<<<dim3(16 * 36, NSPLIT), 128, 0, stream>>>(Qhi, Khi, Vhi, part_o, part_l);
  attn_merge<<<256, 288, 0, stream>>>(part_o, part_l, Zh, Zl);
  gemm_proj<<<dim3(36, 8, 2), 128, 0, stream>>>(Wth + 196608, Wtl + 196608, proj_b,
                                                Zh, Zl, out);
}

// Round 14
// 163.243 us; speedup vs baseline: 1.2101x; 1.0079x over previous
//
#include <hip/hip_runtime.h>
#include <hip/hip_bf16.h>
#include <cstdint>

// Problem constants
#define DIMC  256
#define NH    8
#define HD    32
#define NPIX  2304       // 48*48
#define BATCH 2
#define NSPLIT 6
#define KPS   384        // keys per split (2304/6)
#define KT    32

typedef short s16x8 __attribute__((ext_vector_type(8)));
typedef short s16x4 __attribute__((ext_vector_type(4)));
typedef float f32x4 __attribute__((ext_vector_type(4)));

#define MFMA32(A,B,C) __builtin_amdgcn_mfma_f32_16x16x32_bf16(A,B,C,0,0,0)

// RNA (round-to-nearest-away) bf16 helpers: 1 VALU each.
__device__ inline uint32_t rnau(float x) { return __float_as_uint(x) + 0x8000u; }
__device__ inline uint32_t pk2(uint32_t l_, uint32_t h_) {
  return __builtin_amdgcn_perm(h_, l_, 0x07060302u);
}
__device__ inline float hif(uint32_t a) { return __uint_as_float(a & 0xffff0000u); }

// ---------------------------------------------------------------------------
// Pool: x_avg = (x + box3/9 + box5/25 + box7/49)/4, zero-pad, include_pad
// ---------------------------------------------------------------------------
__global__ __launch_bounds__(256) void pool_kernel(const float* __restrict__ x,
                                                   float* __restrict__ xavg) {
  const int plane = blockIdx.x;
  const float* xp = x + (size_t)plane * NPIX;
  __shared__ float sx[NPIX];
  __shared__ float h3[NPIX], h5[NPIX], h7[NPIX];
  const int t = threadIdx.x;
#pragma unroll
  for (int r = 0; r < 9; ++r) sx[r * 256 + t] = xp[r * 256 + t];
  __syncthreads();
#pragma unroll
  for (int r = 0; r < 9; ++r) {
    int p = r * 256 + t;
    int i = p / 48, j = p - i * 48;
    float a3 = 0.f, a5 = 0.f, a7 = 0.f;
#pragma unroll
    for (int dj = -3; dj <= 3; ++dj) {
      int jj = j + dj;
      if (jj < 0 || jj >= 48) continue;
      float v = sx[i * 48 + jj];
      a7 += v;
      if (dj >= -2 && dj <= 2) a5 += v;
      if (dj >= -1 && dj <= 1) a3 += v;
    }
    h3[p] = a3; h5[p] = a5; h7[p] = a7;
  }
  __syncthreads();
#pragma unroll
  for (int r = 0; r < 9; ++r) {
    int p = r * 256 + t;
    int i = p / 48, j = p - i * 48;
    float b3 = 0.f, b5 = 0.f, b7 = 0.f;
#pragma unroll
    for (int di = -3; di <= 3; ++di) {
      int ii = i + di;
      if (ii < 0 || ii >= 48) continue;
      int q = ii * 48 + j;
      b7 += h7[q];
      if (di >= -2 && di <= 2) b5 += h5[q];
      if (di >= -1 && di <= 1) b3 += h3[q];
    }
    xavg[(size_t)plane * NPIX + p] =
        0.25f * (sx[p] + b3 * (1.f / 9.f) + b5 * (1.f / 25.f) + b7 * (1.f / 49.f));
  }
}

// ---------------------------------------------------------------------------
// Fused converts: blocks 0..287 tconv(x), 288..575 tconv(xavg), 576..703 wconv
// tconv: HI-ONLY (Xl/Al were dead stores — gemm_qkv_hi never reads them;
// proven bit-exact by R13). wconv keeps hi+lo (proj gemm uses both).
// ---------------------------------------------------------------------------
__global__ __launch_bounds__(256) void conv_all(
    const float* __restrict__ x, const float* __restrict__ xavg,
    const float* __restrict__ qw, const float* __restrict__ kvw,
    const float* __restrict__ pw_,
    short* __restrict__ Xh, short* __restrict__ Ah,
    short* __restrict__ Wth, short* __restrict__ Wtl) {
  const int bx = blockIdx.x;
  const int t = threadIdx.x;
  if (bx < 576) {
    const float* src = (bx < 288) ? x : xavg;
    short* dhi = (bx < 288) ? Xh : Ah;
    const int bb = (bx < 288) ? bx : bx - 288;
    const int n0 = (bb % 36) * 64, c0 = ((bb / 36) & 3) * 64, b = bb / 144;
    __shared__ __align__(16) float T[64][68];
    {
      const int c = t >> 2, n4 = (t & 3) * 16;
      const float* sp = src + ((size_t)b * DIMC + c0 + c) * NPIX + n0 + n4;
#pragma unroll
      for (int i2 = 0; i2 < 4; ++i2)
        *(f32x4*)&T[c][n4 + i2 * 4] = *(const f32x4*)(sp + i2 * 4);
    }
    __syncthreads();
    {
      const int n = t >> 2, c4 = (t & 3) * 16;
      float v[16];
#pragma unroll
      for (int i = 0; i < 16; ++i) v[i] = T[c4 + i][n];
      uint32_t a[16];
#pragma unroll
      for (int i = 0; i < 16; ++i) a[i] = rnau(v[i]);
      union { s16x8 s; uint32_t u[4]; } H0, H1;
#pragma unroll
      for (int j = 0; j < 4; ++j) {
        H0.u[j] = pk2(a[2 * j], a[2 * j + 1]);
        H1.u[j] = pk2(a[8 + 2 * j], a[8 + 2 * j + 1]);
      }
      const size_t off = ((size_t)b * NPIX + n0 + n) * DIMC + c0 + c4;
      *(s16x8*)(dhi + off) = H0.s; *(s16x8*)(dhi + off + 8) = H1.s;
    }
  } else {
    const int idx = ((bx - 576) * 256 + t) * 8;
    const float* s;
    int off;
    if (idx < 65536)       { s = qw;  off = idx; }
    else if (idx < 196608) { s = kvw; off = idx - 65536; }
    else                   { s = pw_; off = idx - 196608; }
    f32x4 x0 = *(const f32x4*)(s + off);
    f32x4 x1 = *(const f32x4*)(s + off + 4);
    float v[8] = {x0[0], x0[1], x0[2], x0[3], x1[0], x1[1], x1[2], x1[3]};
    uint32_t a[8], al[8];
#pragma unroll
    for (int i = 0; i < 8; ++i) a[i] = rnau(v[i]);
#pragma unroll
    for (int i = 0; i < 8; ++i) al[i] = rnau(v[i] - hif(a[i]));
    union { s16x8 s; uint32_t u[4]; } H, L;
#pragma unroll
    for (int j = 0; j < 4; ++j) {
      H.u[j] = pk2(a[2 * j], a[2 * j + 1]);
      L.u[j] = pk2(al[2 * j], al[2 * j + 1]);
    }
    *(s16x8*)(Wth + idx) = H.s;
    *(s16x8*)(Wtl + idx) = L.s;
  }
}

// ---------------------------------------------------------------------------
// GEMM body (proj only): 3 MFMAs hi/lo. UNCHANGED.
// ---------------------------------------------------------------------------
__device__ __forceinline__ void gemm_body(
    const short* __restrict__ Wh, const short* __restrict__ Wl,
    const float* __restrict__ bias,
    const short* __restrict__ Inh, const short* __restrict__ Inl,
    float* __restrict__ outf,
    int n0, int o0, int b, float (*Cl)[68]) {
  const int tid = threadIdx.x;
  const int wave = tid >> 6, lane = tid & 63;
  const int g = lane >> 4, q = lane & 15;

  const short* wph = Wh + ((o0 + wave * 16 + q) * DIMC + g * 8);
  const short* wpl = Wl + ((o0 + wave * 16 + q) * DIMC + g * 8);
  const short* iph = Inh + ((size_t)(b * NPIX + n0 + q) * DIMC + g * 8);
  const short* ipl = Inl + ((size_t)(b * NPIX + n0 + q) * DIMC + g * 8);

  f32x4 acc[4] = {{0,0,0,0},{0,0,0,0},{0,0,0,0},{0,0,0,0}};
#pragma unroll
  for (int c0 = 0; c0 < DIMC; c0 += 32) {
    s16x8 ah = *(const s16x8*)(wph + c0);
    s16x8 al = *(const s16x8*)(wpl + c0);
#pragma unroll
    for (int st = 0; st < 4; ++st) {
      s16x8 bh_ = *(const s16x8*)(iph + (size_t)st * 16 * DIMC + c0);
      s16x8 bl_ = *(const s16x8*)(ipl + (size_t)st * 16 * DIMC + c0);
      acc[st] = MFMA32(ah, bh_, acc[st]);
      acc[st] = MFMA32(ah, bl_, acc[st]);
      acc[st] = MFMA32(al, bh_, acc[st]);
    }
  }
#pragma unroll
  for (int st = 0; st < 4; ++st)
#pragma unroll
    for (int r = 0; r < 4; ++r)
      Cl[wave * 16 + g * 4 + r][st * 16 + q] = acc[st][r];
  __syncthreads();

  const int o = tid >> 2, nc = (tid & 3) * 16;
  const float bv = bias[o0 + o];
  float* op = outf + ((size_t)b * DIMC + o0 + o) * NPIX + n0 + nc;
#pragma unroll
  for (int i2 = 0; i2 < 4; ++i2) {
    f32x4 v = *(const f32x4*)&Cl[o][nc + i2 * 4];
    v[0] += bv; v[1] += bv; v[2] += bv; v[3] += bv;
    *(f32x4*)(op + i2 * 4) = v;
  }
}

__global__ __launch_bounds__(128) void gemm_proj(
    const short* __restrict__ Wh, const short* __restrict__ Wl,
    const float* __restrict__ bias,
    const short* __restrict__ Zh, const short* __restrict__ Zl,
    float* __restrict__ out) {
  __shared__ __align__(16) float Cl[32][68];
  gemm_body(Wh, Wl, bias, Zh, Zl, out,
            blockIdx.x * 64, blockIdx.y * 32, blockIdx.z, Cl);
}

// ---------------------------------------------------------------------------
// QKV GEMM, fully specialized hi-only inputs, 2 MFMAs. UNCHANGED from R13.
// ---------------------------------------------------------------------------
__global__ __launch_bounds__(128) void gemm_qkv_hi(
    const short* __restrict__ Wth, const short* __restrict__ Wtl,
    const float* __restrict__ q_b, const float* __restrict__ kv_b,
    const short* __restrict__ Xh, const short* __restrict__ Ah,
    short* __restrict__ Qhi, short* __restrict__ Khi, short* __restrict__ Vhi,
    float qscale) {
  __shared__ __align__(16) float Cl[32][68];
  const int by = blockIdx.y;
  const bool isQ = (by < 8);
  const int o0 = isQ ? by * 32 : (by - 8) * 32;
  const short* Wh = isQ ? Wth : Wth + 65536;
  const short* Wl = isQ ? Wtl : Wtl + 65536;
  const float* bias = isQ ? q_b : kv_b;
  const short* Inh = isQ ? Xh : Ah;
  const float scale = isQ ? qscale : 1.0f;
  short* d1 = isQ ? Qhi : Khi;   // used when o0 < 256 (Q or K)
  const int n0 = blockIdx.x * 64;
  const int b  = blockIdx.z;

  const int tid = threadIdx.x;
  const int wave = tid >> 6, lane = tid & 63;
  const int g = lane >> 4, q = lane & 15;

  const short* wph = Wh + ((o0 + wave * 16 + q) * DIMC + g * 8);
  const short* wpl = Wl + ((o0 + wave * 16 + q) * DIMC + g * 8);
  const short* iph = Inh + ((size_t)(b * NPIX + n0 + q) * DIMC + g * 8);

  f32x4 acc[4] = {{0,0,0,0},{0,0,0,0},{0,0,0,0},{0,0,0,0}};
#pragma unroll
  for (int c0 = 0; c0 < DIMC; c0 += 32) {
    s16x8 ah = *(const s16x8*)(wph + c0);
    s16x8 al = *(const s16x8*)(wpl + c0);
#pragma unroll
    for (int st = 0; st < 4; ++st) {
      s16x8 bh_ = *(const s16x8*)(iph + (size_t)st * 16 * DIMC + c0);
      acc[st] = MFMA32(ah, bh_, acc[st]);
      acc[st] = MFMA32(al, bh_, acc[st]);
    }
  }
#pragma unroll
  for (int st = 0; st < 4; ++st)
#pragma unroll
    for (int r = 0; r < 4; ++r)
      Cl[wave * 16 + g * 4 + r][st * 16 + q] = acc[st][r];
  __syncthreads();

  if (o0 < 256) {
    // Q or K: (C+bias)*scale, hi-only, layout [bh][n][32]
    const int n = tid >> 1, oq = tid & 1;
    const int h = o0 >> 5;
    const float* bp = bias + o0 + oq * 16;
    float v[16];
#pragma unroll
    for (int i = 0; i < 16; ++i) v[i] = (Cl[oq * 16 + i][n] + bp[i]) * scale;
    uint32_t a[16];
#pragma unroll
    for (int i = 0; i < 16; ++i) a[i] = rnau(v[i]);
    union { s16x8 s; uint32_t u[4]; } H0, H1;
#pragma unroll
    for (int j = 0; j < 4; ++j) {
      H0.u[j] = pk2(a[2 * j], a[2 * j + 1]);
      H1.u[j] = pk2(a[8 + 2 * j], a[8 + 2 * j + 1]);
    }
    const size_t off = ((size_t)((b * 8 + h) * NPIX + n0 + n)) * HD + oq * 16;
    *(s16x8*)(d1 + off) = H0.s; *(s16x8*)(d1 + off + 8) = H1.s;
  } else {
    // V hi-only: dst [bh][d][n]
    const int o = tid >> 2, nc = (tid & 3) * 16;
    const int h = (o0 - 256) >> 5;
    const float bv = bias[o0 + o];
    float v[16];
#pragma unroll
    for (int i2 = 0; i2 < 4; ++i2) {
      f32x4 t4 = *(const f32x4*)&Cl[o][nc + i2 * 4];
      v[i2 * 4 + 0] = t4[0] + bv; v[i2 * 4 + 1] = t4[1] + bv;
      v[i2 * 4 + 2] = t4[2] + bv; v[i2 * 4 + 3] = t4[3] + bv;
    }
    uint32_t a[16];
#pragma unroll
    for (int i = 0; i < 16; ++i) a[i] = rnau(v[i]);
    union { s16x8 s; uint32_t u[4]; } H0, H1;
#pragma unroll
    for (int j = 0; j < 4; ++j) {
      H0.u[j] = pk2(a[2 * j], a[2 * j + 1]);
      H1.u[j] = pk2(a[8 + 2 * j], a[8 + 2 * j + 1]);
    }
    const size_t off = ((size_t)((b * 8 + h) * HD + o)) * NPIX + n0 + nc;
    *(s16x8*)(Vhi + off) = H0.s; *(s16x8*)(Vhi + off + 8) = H1.s;
  }
}

// ---------------------------------------------------------------------------
// MFMA flash attention — R12/R13 config (128 threads, 2 waves, 3456 blocks).
// UNCHANGED math: no-max softmax, LDS P round-trip, lag-1 pipeline, MFMA32 PV.
// ---------------------------------------------------------------------------
__global__ __launch_bounds__(128) void attn_mfma(
    const short* __restrict__ Qhi,   // [bh][n][32]
    const short* __restrict__ Khi,   // [bh][n][32]
    const short* __restrict__ Vhi,   // [bh][32][N]
    float* __restrict__ part_o,      // [row][NSPLIT][32]
    float* __restrict__ part_l) {    // [row][NSPLIT]
  const int sb = blockIdx.x;        // 0..575 = 16 bh * 36 qb
  const int bh = sb / 36;
  const int qb = sb % 36;           // 64-row block
  const int split = blockIdx.y;     // 0..NSPLIT-1
  const int tid = threadIdx.x;
  const int wave = tid >> 6, lane = tid & 63;
  const int g = lane >> 4, q = lane & 15;
  const int base = qb * 64 + wave * 32;

  __shared__ __align__(16) short Plds[2][2][16 * 40];
  short* pwA = &Plds[wave][0][0];
  short* pwB = &Plds[wave][1][0];

  const size_t qoff = ((size_t)bh * NPIX + base + q) * HD + g * 8;
  const s16x8 qhA = *(const s16x8*)(Qhi + qoff);
  const s16x8 qhB = *(const s16x8*)(Qhi + qoff + 16 * HD);

  const short* kp = Khi + ((size_t)bh * NPIX + split * KPS + q) * HD + g * 8;
  const short* vp = Vhi + ((size_t)bh * HD + q) * NPIX + split * KPS + g * 8;

  const f32x4 Z4 = {0.f, 0.f, 0.f, 0.f};
  f32x4 OA0 = Z4, OA1 = Z4, OB0 = Z4, OB1 = Z4;
  f32x4 lva = Z4, lvb = Z4;
  s16x8 kb[2][2], vb[2][2], pfA, pfB, vp0, vp1;

  kb[0][0] = *(const s16x8*)(kp);
  kb[0][1] = *(const s16x8*)(kp + 16 * HD);
  vb[0][0] = *(const s16x8*)(vp);
  vb[0][1] = *(const s16x8*)(vp + 16 * NPIX);

#pragma unroll
  for (int t = 0; t < KPS / KT; ++t) {
    const int cur = t & 1, nxt = cur ^ 1;
    if (t < KPS / KT - 1) {
      const short* kpn = kp + (t + 1) * (KT * HD);
      const short* vpn = vp + (t + 1) * KT;
      kb[nxt][0] = *(const s16x8*)(kpn);
      kb[nxt][1] = *(const s16x8*)(kpn + 16 * HD);
      vb[nxt][0] = *(const s16x8*)(vpn);
      vb[nxt][1] = *(const s16x8*)(vpn + 16 * NPIX);
    }
    f32x4 SA0 = MFMA32(kb[cur][0], qhA, Z4);
    f32x4 SA1 = MFMA32(kb[cur][1], qhA, Z4);
    f32x4 SB0 = MFMA32(kb[cur][0], qhB, Z4);
    f32x4 SB1 = MFMA32(kb[cur][1], qhB, Z4);
    if (t > 0) {   // PV for tile t-1 (pf read issued last iter)
      OA0 = MFMA32(vp0, pfA, OA0);
      OA1 = MFMA32(vp1, pfA, OA1);
      OB0 = MFMA32(vp0, pfB, OB0);
      OB1 = MFMA32(vp1, pfB, OB1);
    }
    {   // q-tile A softmax weights
      f32x4 p0, p1;
#pragma unroll
      for (int r = 0; r < 4; ++r) { p0[r] = exp2f(SA0[r]); p1[r] = exp2f(SA1[r]); }
      lva += p0 + p1;
      uint2 w0, w1;
      w0.x = pk2(rnau(p0[0]), rnau(p0[1])); w0.y = pk2(rnau(p0[2]), rnau(p0[3]));
      w1.x = pk2(rnau(p1[0]), rnau(p1[1])); w1.y = pk2(rnau(p1[2]), rnau(p1[3]));
      *(uint2*)&pwA[q * 40 + g * 4] = w0;
      *(uint2*)&pwA[q * 40 + 16 + g * 4] = w1;
    }
    {   // q-tile B
      f32x4 p0, p1;
#pragma unroll
      for (int r = 0; r < 4; ++r) { p0[r] = exp2f(SB0[r]); p1[r] = exp2f(SB1[r]); }
      lvb += p0 + p1;
      uint2 w0, w1;
      w0.x = pk2(rnau(p0[0]), rnau(p0[1])); w0.y = pk2(rnau(p0[2]), rnau(p0[3]));
      w1.x = pk2(rnau(p1[0]), rnau(p1[1])); w1.y = pk2(rnau(p1[2]), rnau(p1[3]));
      *(uint2*)&pwB[q * 40 + g * 4] = w0;
      *(uint2*)&pwB[q * 40 + 16 + g * 4] = w1;
    }
    vp0 = vb[cur][0]; vp1 = vb[cur][1];
    pfA = *(const s16x8*)&pwA[q * 40 + g * 8];   // consumed next iter
    pfB = *(const s16x8*)&pwB[q * 40 + g * 8];
  }
  // epilogue PV for last tile
  OA0 = MFMA32(vp0, pfA, OA0);
  OA1 = MFMA32(vp1, pfA, OA1);
  OB0 = MFMA32(vp0, pfB, OB0);
  OB1 = MFMA32(vp1, pfB, OB1);

  float lA = (lva[0] + lva[1]) + (lva[2] + lva[3]);
  float lB = (lvb[0] + lvb[1]) + (lvb[2] + lvb[3]);
  lA += __shfl_xor(lA, 16); lA += __shfl_xor(lA, 32);
  lB += __shfl_xor(lB, 16); lB += __shfl_xor(lB, 32);

  const int rowA = bh * NPIX + base + q;
  const int rowB = rowA + 16;
  float* poA = part_o + ((size_t)rowA * NSPLIT + split) * HD;
  float* poB = part_o + ((size_t)rowB * NSPLIT + split) * HD;
  *(f32x4*)(poA + g * 4) = OA0;
  *(f32x4*)(poA + 16 + g * 4) = OA1;
  *(f32x4*)(poB + g * 4) = OB0;
  *(f32x4*)(poB + 16 + g * 4) = OB1;
  if (g == 0) {
    part_l[(size_t)rowA * NSPLIT + split] = lA;
    part_l[(size_t)rowB * NSPLIT + split] = lB;
  }
}

// ---------------------------------------------------------------------------
// Merge splits, emit SCRAMBLED z hi/lo [b][p][256]. 256 blocks. UNCHANGED.
// ---------------------------------------------------------------------------
__global__ __launch_bounds__(288) void attn_merge(const float* __restrict__ part_o,
                                                  const float* __restrict__ part_l,
                                                  short* __restrict__ zh,
                                                  short* __restrict__ zl) {
  const int blk = blockIdx.x;          // 256 = 16 bh * 16
  const int bh = blk >> 4;
  const int n0 = (blk & 15) * 144;
  const int head = bh & 7, b = bh >> 3;
  const int t = threadIdx.x;
  __shared__ __align__(16) float T[144][36];
  {
    const int r = t >> 1, uh = (t & 1) * 4;   // r in 0..143
    const int idx = bh * NPIX + n0 + r;
    const float* pl = part_l + (size_t)idx * NSPLIT;
    float L = 0.f;
#pragma unroll
    for (int s = 0; s < NSPLIT; ++s) L += pl[s];
    const float inv = 1.f / L;
    const float* po = part_o + (size_t)idx * (NSPLIT * HD);
#pragma unroll
    for (int u = 0; u < 4; ++u) {
      f32x4 v = {0.f, 0.f, 0.f, 0.f};
#pragma unroll
      for (int s = 0; s < NSPLIT; ++s)
        v += *(const f32x4*)(po + s * HD + (uh + u) * 4);
      v[0] *= inv; v[1] *= inv; v[2] *= inv; v[3] *= inv;
      *(f32x4*)&T[r][(uh + u) * 4] = v;
    }
  }
  __syncthreads();
  {
    const int r9 = t / 32, dd = t & 31;    // r9 in 0..8
    const int p = r9 * 256 + head * HD + dd;
    const int c0 = n0 / 9;                  // 16 channels per chunk
    float v[16];
#pragma unroll
    for (int j = 0; j < 16; ++j) v[j] = T[9 * j + r9][dd];
    uint32_t a[16], al[16];
#pragma unroll
    for (int j = 0; j < 16; ++j) a[j] = rnau(v[j]);
#pragma unroll
    for (int j = 0; j < 16; ++j) al[j] = rnau(v[j] - hif(a[j]));
    const size_t off = ((size_t)b * NPIX + p) * DIMC + c0;
#pragma unroll
    for (int c8 = 0; c8 < 2; ++c8) {
      union { s16x8 s; uint32_t u[4]; } H, L;
#pragma unroll
      for (int j = 0; j < 4; ++j) {
        H.u[j] = pk2(a[c8 * 8 + 2 * j], a[c8 * 8 + 2 * j + 1]);
        L.u[j] = pk2(al[c8 * 8 + 2 * j], al[c8 * 8 + 2 * j + 1]);
      }
      *(s16x8*)(zh + off + c8 * 8) = H.s;
      *(s16x8*)(zl + off + c8 * 8) = L.s;
    }
  }
}

// ---------------------------------------------------------------------------
extern "C" void kernel_launch(void* const* d_in, const int* in_sizes, int n_in,
                              void* d_out, int out_size, void* d_ws, size_t ws_size,
                              hipStream_t stream) {
  const float* x      = (const float*)d_in[0];
  const float* q_w    = (const float*)d_in[1];
  const float* q_b    = (const float*)d_in[2];
  const float* kv_w   = (const float*)d_in[3];
  const float* kv_b   = (const float*)d_in[4];
  const float* proj_w = (const float*)d_in[5];
  const float* proj_b = (const float*)d_in[6];
  float* out = (float*)d_out;

  // Workspace (42.0 MB; 43.6 MB proven available in R1). Same layout as R13
  // (Xl/Al slots now unused — kept for offset stability).
  char* w = (char*)d_ws;
  float* xavg = (float*)w;                       // 4,718,592
  short* Xh   = (short*)(w + 4718592);
  short* Ah   = (short*)(w + 9437184);
  float* part_o = (float*)w;                     // 28,311,552 (aliases above)
  short* Wth  = (short*)(w + 28311552);          // 524,288
  short* Wtl  = (short*)(w + 28835840);
  short* Qhi  = (short*)(w + 29360128);          // 2,359,296
  short* Khi  = (short*)(w + 31719424);
  short* Vhi  = (short*)(w + 34078720);
  float* part_l = (float*)(w + 36438016);        // 884,736
  short* Zh   = (short*)(w + 37322752);
  short* Zl   = (short*)(w + 39682048);          // ends 42,041,344

  const float qscale = 0.17677669529663689f * 1.4426950408889634f; // d^-0.5*log2(e)

  pool_kernel<<<BATCH * DIMC, 256, 0, stream>>>(x, xavg);
  conv_all<<<704, 256, 0, stream>>>(x, xavg, q_w, kv_w, proj_w,
                                    Xh, Ah, Wth, Wtl);
  gemm_qkv_hi<<<dim3(36, 24, 2), 128, 0, stream>>>(Wth, Wtl, q_b, kv_b,
                                                   Xh, Ah, Qhi, Khi, Vhi, qscale);
  attn_mfma<<<dim3(16 * 36, NSPLIT), 128, 0, stream>>>(Qhi, Khi, Vhi, part_o, part_l);
  attn_merge<<<256, 288, 0, stream>>>(part_o, part_l, Zh, Zl);
  gemm_proj<<<dim3(36, 8, 2), 128, 0, stream>>>(Wth + 196608, Wtl + 196608, proj_b,
                                                Zh, Zl, out);
}